// Round 11
// baseline (371.004 us; speedup 1.0000x reference)
//
#include <hip/hip_runtime.h>
#include <stdint.h>

typedef __attribute__((ext_vector_type(8))) short bf16x8;   // 8 bf16 in 4 VGPRs
typedef __attribute__((ext_vector_type(4))) float f32x4;

#define DM   1024
#define TT   1024
#define NH   16
#define DKH  64
#define SPAN 512
#define S2   1024   // 2*SPAN
#define MT   4096   // 4*TT rows

__device__ __forceinline__ unsigned short f2b(float f) {
  unsigned int u = __builtin_bit_cast(unsigned int, f);
  u = (u + 0x7FFFu + ((u >> 16) & 1u)) >> 16;   // RTNE
  return (unsigned short)u;
}
__device__ __forceinline__ float b2f(unsigned short h) {
  unsigned int u = ((unsigned int)h) << 16;
  return __builtin_bit_cast(float, u);
}

// XOR-swizzled LDS index for row-major [R][64]-short tiles (128 B rows).
// 16B chunks permuted within each row: phys_chunk = log_chunk ^ (row & 7).
__device__ __forceinline__ int swz(int row, int col) {
  return (row << 6) + ((((col >> 3) ^ (row & 7)) << 3) | (col & 7));
}

// async global->LDS 16B: LDS dest = wave-uniform base + lane*16 (linear);
// swizzle achieved by inverse-permuting the per-lane GLOBAL source column.
__device__ __forceinline__ void gl16(const void* g, void* l) {
  __builtin_amdgcn_global_load_lds(
      (const __attribute__((address_space(1))) unsigned int*)g,
      (__attribute__((address_space(3))) unsigned int*)l, 16, 0, 0);
}

// ---------------- batched f32 -> bf16 convert (one launch for all tensors) ----------------
struct CvtArgs {
  const float* src[8];
  unsigned short* dst[8];
  int n[8];
};
__global__ void cvt_multi(CvtArgs a) {
  const int ti = blockIdx.y;
  const float* __restrict__ in = a.src[ti];
  unsigned short* __restrict__ out = a.dst[ti];
  const int n = a.n[ti];
  int i = (blockIdx.x * blockDim.x + threadIdx.x) * 4;
  int stride = gridDim.x * blockDim.x * 4;
  for (; i < n; i += stride) {
    float4 v = *(const float4*)(in + i);
    ushort4 o;
    o.x = f2b(v.x); o.y = f2b(v.y); o.z = f2b(v.z); o.w = f2b(v.w);
    *(ushort4*)(out + i) = o;
  }
}

// ---------------- multi-z bf16 GEMM ----------------
// z < nzA: A = A0 (M0 rows, C at z*sC);  z >= nzA: A = A1 (M1 rows, C at nzA*sC + (z-nzA)*sC2)
// B (weights) contiguous at z*sB. alpha = a0 for z==0 or z==4, else 1.
// mode per z (4 bits in `modes`): 0 = f32 out, 1 = bf16 out, 2 = bf16 TRANSPOSED out C[col*Mz+row]
__global__ __launch_bounds__(256) void gemm_bt(
    const unsigned short* __restrict__ A0, const unsigned short* __restrict__ A1,
    const unsigned short* __restrict__ B,
    const float* __restrict__ bias0, const float* __restrict__ bias1,
    const float* __restrict__ bias2, const float* __restrict__ bias3,
    const float* __restrict__ bias4,
    void* __restrict__ C,
    int M0, int M1, int K, int lda, int ldb, int ldc,
    long long sB, long long sC, long long sC2,
    float a0, int modes, int nzA)
{
  __shared__ unsigned short Al[128 * 72];
  __shared__ unsigned short Bl[128 * 72];
  const int t = threadIdx.x;
  const int w = t >> 6, l = t & 63;
  const int g = l >> 4, li = l & 15;
  const int wr = w >> 1, wc = w & 1;
  const int row0 = blockIdx.x * 128, col0 = blockIdx.y * 128;
  const int z = blockIdx.z;
  const int Mz = (z < nzA) ? M0 : M1;
  if (row0 >= Mz) return;   // uniform early-exit for short (PK/PQ) slices
  const unsigned short* Ab = (z < nzA) ? A0 : A1;
  const unsigned short* Bb = B + (long long)z * sB;

  f32x4 acc[4][4];
#pragma unroll
  for (int m = 0; m < 4; m++)
#pragma unroll
    for (int n = 0; n < 4; n++) acc[m][n] = (f32x4){0.f, 0.f, 0.f, 0.f};

  for (int k0 = 0; k0 < K; k0 += 64) {
    __syncthreads();
#pragma unroll
    for (int i = 0; i < 4; i++) {
      int c = t + 256 * i;
      int r = c >> 3, c8 = (c & 7) * 8;
      *(bf16x8*)&Al[r * 72 + c8] = *(const bf16x8*)&Ab[(long long)(row0 + r) * lda + k0 + c8];
      *(bf16x8*)&Bl[r * 72 + c8] = *(const bf16x8*)&Bb[(long long)(col0 + r) * ldb + k0 + c8];
    }
    __syncthreads();
#pragma unroll
    for (int kk = 0; kk < 2; kk++) {
      bf16x8 af[4], bfr[4];
#pragma unroll
      for (int m = 0; m < 4; m++) af[m]  = *(bf16x8*)&Al[(wr * 64 + m * 16 + li) * 72 + kk * 32 + g * 8];
#pragma unroll
      for (int n = 0; n < 4; n++) bfr[n] = *(bf16x8*)&Bl[(wc * 64 + n * 16 + li) * 72 + kk * 32 + g * 8];
#pragma unroll
      for (int m = 0; m < 4; m++)
#pragma unroll
        for (int n = 0; n < 4; n++)
          acc[m][n] = __builtin_amdgcn_mfma_f32_16x16x32_bf16(af[m], bfr[n], acc[m][n], 0, 0, 0);
    }
  }

  const float alpha = (z == 0 || z == 4) ? a0 : 1.0f;
  const float* bias = z == 0 ? bias0 : (z == 1 ? bias1 : (z == 2 ? bias2 : (z == 3 ? bias3 : bias4)));
  const int mode = (modes >> (4 * z)) & 15;
  const long long zoff = (z < nzA) ? (long long)z * sC
                                   : (long long)nzA * sC + (long long)(z - nzA) * sC2;

#pragma unroll
  for (int m = 0; m < 4; m++) {
    int row = row0 + wr * 64 + m * 16 + g * 4;
#pragma unroll
    for (int n = 0; n < 4; n++) {
      int col = col0 + wc * 64 + n * 16 + li;
      float bv = bias ? bias[col] : 0.0f;
      if (mode == 2) {
        ushort4 st;
        st.x = f2b((acc[m][n][0] + bv) * alpha);
        st.y = f2b((acc[m][n][1] + bv) * alpha);
        st.z = f2b((acc[m][n][2] + bv) * alpha);
        st.w = f2b((acc[m][n][3] + bv) * alpha);
        *(ushort4*)&((unsigned short*)C)[zoff + (long long)col * Mz + row] = st;
      } else {
#pragma unroll
        for (int r = 0; r < 4; r++) {
          float v = (acc[m][n][r] + bv) * alpha;
          long long idx = zoff + (long long)(row + r) * ldc + col;
          if (mode == 1) ((unsigned short*)C)[idx] = f2b(v);
          else           ((float*)C)[idx] = v;
        }
      }
    }
  }
}

// ---------------- fully fused disentangled attention ----------------
// ROUND-10 STRUCTURE with ONE change: interior-tile gather-address precompute.
// For tiles with 64 <= d0 <= 960 (block-uniform; ~75% of tiles) no clamp fires
// and w0 == d0-64, so the 16 Pq gather addresses are loop constants and the 16
// Ct addresses toggle by XOR 4096 with (d0&64). Edge tiles keep the exact
// original code path (bit-identical results either way).
// grid 1024 (flat, XCD-swizzled); block 256 (4 waves x 16 q-rows each).
// score'[q,k] = Qs.K + Qs.PK[s] + K.PQs[s], s = clamp(k-q+512, 0, 1023)
// (scale*log2e pre-folded into Q and PQ projections; softmax uses exp2)
// LDS 49152 B -> 3 blocks/CU:
//   Kl  [64][64]   K tile (shared); P tile after [D]
//   Vtl [64][64]   V^T tile, staged linearly from pre-transposed VT
//   Ct  [128][64]  persistent circular CtT[s&127][q] (raw PK in slide slots)
//   Pq  [128][64]  raw PQ window -> PtT[j][k] per tile
__global__ __launch_bounds__(256, 3) void attn_fused(
    const unsigned short* __restrict__ Qb, const unsigned short* __restrict__ Kb,
    const unsigned short* __restrict__ VT,
    const unsigned short* __restrict__ PKb, const unsigned short* __restrict__ PQb,
    unsigned short* __restrict__ ctxb)
{
  __shared__ unsigned short Kl[64 * 64];   // K tile; P tile after [D]
  __shared__ unsigned short Vtl[64 * 64];  // V^T tile
  __shared__ unsigned short Ct[128 * 64];  // circular CtT[s&127][q]
  __shared__ unsigned short Pq[128 * 64];  // raw PQ window -> PtT[j][k]

  const int t = threadIdx.x, w = t >> 6, l = t & 63, g = l >> 4, li = l & 15;
  const int lr = l >> 3;                   // lane's row-in-group (== row&7 in staging)
  const int sc8 = ((t & 7) ^ lr) * 8;      // inverse-swizzled source col (shorts)
  // XCD-aware role swizzle: each XCD gets 128 contiguous roles
  const int bid = blockIdx.x;
  const int role = (bid & 7) * 128 + (bid >> 3);
  const int q0 = (role & 15) * 64;
  const int h = (role >> 4) & 15;
  const int b = role >> 8;
  const long long qkbase = ((long long)b * TT) * DM + h * DKH;
  const long long vtb = (long long)(h * DKH) * MT + (long long)b * TT;  // + d*MT + k
  const int hbase = h * DKH;

  // Q fragments: direct global, once per block (loop-invariant)
  bf16x8 aq[2];
#pragma unroll
  for (int kk = 0; kk < 2; kk++)
    aq[kk] = *(const bf16x8*)&Qb[qkbase + (long long)(q0 + w * 16 + li) * DM + kk * 32 + g * 8];

  // interior-tile gather addresses (see header comment):
  //   pqA[f][r] = swz(64 + ki - qi, ki)           (tile-invariant)
  //   ctA[f][r] = swz((ki-qi) & 127, qi)          (XOR 4096 when d0&64)
  int pqA[4][4], ctA[4][4];
#pragma unroll
  for (int f = 0; f < 4; f++)
#pragma unroll
    for (int r = 0; r < 4; r++) {
      const int qi = w * 16 + g * 4 + r;
      const int ki = f * 16 + li;
      const int e = ki - qi;
      pqA[f][r] = swz(64 + e, ki);
      const int s0 = e & 127;
      ctA[f][r] = (s0 << 6) + ((((qi >> 3) ^ (s0 & 7)) << 3) | (qi & 7));
    }

  // ---- prologue: fill circular Ct for the kt=0 window ----
  int w0 = SPAN - q0 - 64;
  w0 = w0 < 0 ? 0 : (w0 > S2 - 128 ? S2 - 128 : w0);   // always a multiple of 64
#pragma unroll
  for (int i = 0; i < 4; i++) {
    const int wr0l = w * 8 + 32 * i;                   // logical row base 0..120
    const int jr = wr0l + lr;                          // this lane's logical row
    const int wr0 = (w0 + wr0l) & 127;                 // wrapped wave-uniform LDS row base
    gl16(&PKb[(long long)(w0 + jr) * DM + hbase + sc8], &Ct[wr0 * 64]);
  }
  __syncthreads();
  {
    f32x4 cp[8];
#pragma unroll
    for (int jb = 0; jb < 8; jb++) cp[jb] = (f32x4){0.f, 0.f, 0.f, 0.f};
    __builtin_amdgcn_s_setprio(1);
#pragma unroll
    for (int kk = 0; kk < 2; kk++)
#pragma unroll
      for (int jb = 0; jb < 8; jb++) {
        bf16x8 pkf = *(bf16x8*)&Ct[swz(jb * 16 + li, kk * 32 + g * 8)];
        cp[jb] = __builtin_amdgcn_mfma_f32_16x16x32_bf16(aq[kk], pkf, cp[jb], 0, 0, 0);
      }
    __builtin_amdgcn_s_setprio(0);
    __syncthreads();  // all raw reads done before overwrite
#pragma unroll
    for (int jb = 0; jb < 8; jb++) {
      ushort4 a;
      a.x = f2b(cp[jb][0]); a.y = f2b(cp[jb][1]);
      a.z = f2b(cp[jb][2]); a.w = f2b(cp[jb][3]);
      *(ushort4*)&Ct[swz(jb * 16 + li, w * 16 + g * 4)] = a;   // own-wave cols only
    }
  }

  f32x4 o[4];
#pragma unroll
  for (int n = 0; n < 4; n++) o[n] = (f32x4){0.f, 0.f, 0.f, 0.f};
  float mrow[4], lrow[4];
#pragma unroll
  for (int r = 0; r < 4; r++) { mrow[r] = -1e30f; lrow[r] = 0.f; }

  for (int kt = 0; kt < TT / 64; kt++) {
    const int k0 = kt * 64;
    const int d0 = k0 - q0 + SPAN;                       // block-uniform
    int w0n = d0 - 64;
    w0n = w0n < 0 ? 0 : (w0n > S2 - 128 ? S2 - 128 : w0n);
    const bool slide = (w0n != w0);                      // step is always exactly +64
    const int sb = w0 & 127;                             // slots replaced on slide (0 or 64)
    const int newrow0 = w0 + 128;                        // abs first new row on slide
    w0 = w0n;

    __syncthreads();  // [A] prev tile readers of Kl/Vtl/Ct/Pq done
    // stage K tile + V^T tile (global_load_lds, inverse-swizzled source)
#pragma unroll
    for (int i = 0; i < 2; i++) {
      const int wr0 = w * 8 + 32 * i;                    // wave-uniform LDS row base
      const int r = wr0 + lr;                            // lane's row
      gl16(&Kb[qkbase + (long long)(k0 + r) * DM + sc8], &Kl[wr0 * 64]);
      gl16(&VT[vtb + (long long)r * MT + k0 + sc8],      &Vtl[wr0 * 64]);
    }
    // stage raw PQ window (every tile; overwritten by PtT)
#pragma unroll
    for (int i = 0; i < 4; i++) {
      const int wr0 = w * 8 + 32 * i;                    // 0..120
      const int jr = wr0 + lr;
      gl16(&PQb[(long long)(w0 + jr) * DM + hbase + sc8], &Pq[wr0 * 64]);
    }
    // stage 64 new raw PK rows on slide (into recycled Ct slots)
    if (slide) {
#pragma unroll
      for (int i = 0; i < 2; i++) {
        const int wr0l = w * 8 + 32 * i;                 // 0..56
        const int jr = wr0l + lr;
        gl16(&PKb[(long long)(newrow0 + jr) * DM + hbase + sc8], &Ct[(sb + wr0l) * 64]);
      }
    }
    __syncthreads();  // [B] staging visible (vmcnt drained by barrier)

    // K strip A-fragments (for p2c)
    bf16x8 ak[2];
#pragma unroll
    for (int kk = 0; kk < 2; kk++) ak[kk] = *(bf16x8*)&Kl[swz(w * 16 + li, kk * 32 + g * 8)];

    __builtin_amdgcn_s_setprio(1);
    // QK^T: 16 q-rows x 64 k-cols (Q pre-scaled by scale*log2e)
    f32x4 sc[4];
#pragma unroll
    for (int f = 0; f < 4; f++) sc[f] = (f32x4){0.f, 0.f, 0.f, 0.f};
#pragma unroll
    for (int kk = 0; kk < 2; kk++)
#pragma unroll
      for (int f = 0; f < 4; f++) {
        bf16x8 bk = *(bf16x8*)&Kl[swz(f * 16 + li, kk * 32 + g * 8)];
        sc[f] = __builtin_amdgcn_mfma_f32_16x16x32_bf16(aq[kk], bk, sc[f], 0, 0, 0);
      }
    // c2p for the 64 new slots only (slide tiles)
    f32x4 cp2[4];
#pragma unroll
    for (int jb = 0; jb < 4; jb++) cp2[jb] = (f32x4){0.f, 0.f, 0.f, 0.f};
    if (slide) {
#pragma unroll
      for (int kk = 0; kk < 2; kk++)
#pragma unroll
        for (int jb = 0; jb < 4; jb++) {
          bf16x8 pkf = *(bf16x8*)&Ct[swz(sb + jb * 16 + li, kk * 32 + g * 8)];
          cp2[jb] = __builtin_amdgcn_mfma_f32_16x16x32_bf16(aq[kk], pkf, cp2[jb], 0, 0, 0);
        }
    }
    // p2c restricted to this wave's needed rows: s in [d0+16w-63, d0+16w+15]
    int loA = d0 + w * 16 - 63; loA = loA < w0 ? w0 : loA;
    int hiA = d0 + w * 16 + 15; hiA = hiA > w0 + 127 ? w0 + 127 : hiA;
    const int jb_lo = (loA - w0) >> 4;
    const int jb_n  = ((hiA - w0) >> 4) - jb_lo;   // 0..5 inclusive extra blocks
    f32x4 pp[6];
#pragma unroll
    for (int u = 0; u < 6; u++) pp[u] = (f32x4){0.f, 0.f, 0.f, 0.f};
#pragma unroll
    for (int kk = 0; kk < 2; kk++)
#pragma unroll
      for (int u = 0; u < 6; u++)
        if (u <= jb_n) {
          bf16x8 pqf = *(bf16x8*)&Pq[swz((jb_lo + u) * 16 + li, kk * 32 + g * 8)];
          pp[u] = __builtin_amdgcn_mfma_f32_16x16x32_bf16(ak[kk], pqf, pp[u], 0, 0, 0);
        }
    __builtin_amdgcn_s_setprio(0);
    __syncthreads();  // [C] all raw window reads + Kl fragment reads done

    // overwrite with transposed products (own-wave columns)
    if (slide) {
#pragma unroll
      for (int jb = 0; jb < 4; jb++) {
        ushort4 a;
        a.x = f2b(cp2[jb][0]); a.y = f2b(cp2[jb][1]);
        a.z = f2b(cp2[jb][2]); a.w = f2b(cp2[jb][3]);
        *(ushort4*)&Ct[swz(sb + jb * 16 + li, w * 16 + g * 4)] = a;
      }
    }
#pragma unroll
    for (int u = 0; u < 6; u++)
      if (u <= jb_n) {
        ushort4 a;
        a.x = f2b(pp[u][0]); a.y = f2b(pp[u][1]);
        a.z = f2b(pp[u][2]); a.w = f2b(pp[u][3]);
        *(ushort4*)&Pq[swz((jb_lo + u) * 16 + li, w * 16 + g * 4)] = a;
      }
    __syncthreads();  // [D] PtT visible cross-wave (Ct gather is wave-private)

    // combine + online softmax (base-2 domain)
    float p[4][4];
    float tmax[4] = {-1e30f, -1e30f, -1e30f, -1e30f};
    const bool interior = (d0 >= 64) && (d0 <= 960);     // block-uniform branch
    if (interior) {
      const int ctxor = (d0 & 64) << 6;                  // 0 or 4096
#pragma unroll
      for (int f = 0; f < 4; f++)
#pragma unroll
        for (int r = 0; r < 4; r++) {
          float v = sc[f][r] + b2f(Ct[ctA[f][r] ^ ctxor]) + b2f(Pq[pqA[f][r]]);
          p[f][r] = v;
          tmax[r] = fmaxf(tmax[r], v);
        }
    } else {
#pragma unroll
      for (int f = 0; f < 4; f++)
#pragma unroll
        for (int r = 0; r < 4; r++) {
          int qi = w * 16 + g * 4 + r;
          int ki = f * 16 + li;
          int sraw = d0 + ki - qi;
          int scl = sraw < 0 ? 0 : (sraw > S2 - 1 ? S2 - 1 : sraw);
          int slot = scl & 127;
          int j = scl - w0;
          float v = sc[f][r] + b2f(Ct[swz(slot, qi)]) + b2f(Pq[swz(j, ki)]);
          p[f][r] = v;
          tmax[r] = fmaxf(tmax[r], v);
        }
    }
#pragma unroll
    for (int msk = 1; msk <= 8; msk <<= 1)
#pragma unroll
      for (int r = 0; r < 4; r++) tmax[r] = fmaxf(tmax[r], __shfl_xor(tmax[r], msk));
    float corr[4];
#pragma unroll
    for (int r = 0; r < 4; r++) {
      float mn = fmaxf(mrow[r], tmax[r]);
      corr[r] = exp2f(mrow[r] - mn);
      mrow[r] = mn;
      lrow[r] *= corr[r];
    }
#pragma unroll
    for (int n = 0; n < 4; n++)
#pragma unroll
      for (int r = 0; r < 4; r++) o[n][r] *= corr[r];

    float ps[4] = {0.f, 0.f, 0.f, 0.f};
#pragma unroll
    for (int f = 0; f < 4; f++)
#pragma unroll
      for (int r = 0; r < 4; r++) {
        float e = exp2f(p[f][r] - mrow[r]);
        ps[r] += e;
        Kl[swz(w * 16 + g * 4 + r, f * 16 + li)] = f2b(e);  // P over Kl: own wave's rows
      }
#pragma unroll
    for (int msk = 1; msk <= 8; msk <<= 1)
#pragma unroll
      for (int r = 0; r < 4; r++) ps[r] += __shfl_xor(ps[r], msk);
#pragma unroll
    for (int r = 0; r < 4; r++) lrow[r] += ps[r];

    // PV: P rows wave-private (in-wave LDS ordering by compiler); V^T from LDS
    __builtin_amdgcn_s_setprio(1);
#pragma unroll
    for (int kk = 0; kk < 2; kk++) {
      bf16x8 ap = *(bf16x8*)&Kl[swz(w * 16 + li, kk * 32 + g * 8)];
#pragma unroll
      for (int n = 0; n < 4; n++) {
        bf16x8 bvf = *(bf16x8*)&Vtl[swz(n * 16 + li, kk * 32 + g * 8)];
        o[n] = __builtin_amdgcn_mfma_f32_16x16x32_bf16(ap, bvf, o[n], 0, 0, 0);
      }
    }
    __builtin_amdgcn_s_setprio(0);
  }

  // epilogue: ctx[b, q, h*64+d] bf16
#pragma unroll
  for (int n = 0; n < 4; n++)
#pragma unroll
    for (int r = 0; r < 4; r++) {
      int q = q0 + w * 16 + g * 4 + r;
      float val = o[n][r] / lrow[r];
      ctxb[((long long)b * TT + q) * DM + h * DKH + n * 16 + li] = f2b(val);
    }
}

// ---------------- host ----------------
extern "C" void kernel_launch(void* const* d_in, const int* in_sizes, int n_in,
                              void* d_out, int out_size, void* d_ws, size_t ws_size,
                              hipStream_t stream) {
  const float* x   = (const float*)d_in[0];
  const float* Wq  = (const float*)d_in[1];
  const float* bq  = (const float*)d_in[2];
  const float* Wk  = (const float*)d_in[3];
  const float* bk  = (const float*)d_in[4];
  const float* Wv  = (const float*)d_in[5];
  const float* bv  = (const float*)d_in[6];
  const float* Wo  = (const float*)d_in[7];
  const float* bo  = (const float*)d_in[8];
  const float* Wpk = (const float*)d_in[9];
  const float* bpk = (const float*)d_in[10];
  const float* Wpq = (const float*)d_in[11];
  const float* bpq = (const float*)d_in[12];
  const float* rel = (const float*)d_in[13];

  uint8_t* ws = (uint8_t*)d_ws;
  size_t off = 0;
  auto alloc = [&](size_t bytes) -> void* {
    void* p = ws + off;
    off += (bytes + 255) & ~(size_t)255;
    return p;
  };
  // Weight order Wq,Wk,Wv,Wpk,Wpq MUST be contiguous (z-strided B in the fused launch);
  // Qb,Kb,VT,PKb,PQb MUST be contiguous (z-strided C). All sizes are 256-multiples.
  unsigned short* xb   = (unsigned short*)alloc((size_t)MT * DM * 2);
  unsigned short* Wqb  = (unsigned short*)alloc((size_t)DM * DM * 2);
  unsigned short* Wkb  = (unsigned short*)alloc((size_t)DM * DM * 2);
  unsigned short* Wvb  = (unsigned short*)alloc((size_t)DM * DM * 2);
  unsigned short* Wpkb = (unsigned short*)alloc((size_t)DM * DM * 2);
  unsigned short* Wpqb = (unsigned short*)alloc((size_t)DM * DM * 2);
  unsigned short* Wob  = (unsigned short*)alloc((size_t)DM * DM * 2);
  unsigned short* reb  = (unsigned short*)alloc((size_t)S2 * DM * 2);
  unsigned short* Qb   = (unsigned short*)alloc((size_t)MT * DM * 2);
  unsigned short* Kb   = (unsigned short*)alloc((size_t)MT * DM * 2);
  unsigned short* VT   = (unsigned short*)alloc((size_t)MT * DM * 2);  // V^T: [h*64+d][b*1024+k]
  unsigned short* PKb  = (unsigned short*)alloc((size_t)S2 * DM * 2);
  unsigned short* PQb  = (unsigned short*)alloc((size_t)S2 * DM * 2);
  unsigned short* ctxb = (unsigned short*)alloc((size_t)MT * DM * 2);

  // scale * log2(e): softmax runs in base-2 domain (exp2f)
  const float scale2 = 0.07216878364870323f * 1.4426950408889634f;

  // one batched convert launch for all 8 fp32 tensors
  CvtArgs ca;
  ca.src[0] = x;   ca.dst[0] = xb;   ca.n[0] = MT * DM;
  ca.src[1] = Wq;  ca.dst[1] = Wqb;  ca.n[1] = DM * DM;
  ca.src[2] = Wk;  ca.dst[2] = Wkb;  ca.n[2] = DM * DM;
  ca.src[3] = Wv;  ca.dst[3] = Wvb;  ca.n[3] = DM * DM;
  ca.src[4] = Wpk; ca.dst[4] = Wpkb; ca.n[4] = DM * DM;
  ca.src[5] = Wpq; ca.dst[5] = Wpqb; ca.n[5] = DM * DM;
  ca.src[6] = Wo;  ca.dst[6] = Wob;  ca.n[6] = DM * DM;
  ca.src[7] = rel; ca.dst[7] = reb;  ca.n[7] = S2 * DM;
  cvt_multi<<<dim3(1024, 8), dim3(256), 0, stream>>>(ca);

  // ALL FIVE projections in one launch:
  //   z0=Q (A=xb, alpha=scale2, bf16), z1=K (bf16), z2=V (bf16 transposed -> VT),
  //   z3=PK (A=reb, alpha=1, bf16), z4=PQ (A=reb, alpha=scale2, bf16)
  gemm_bt<<<dim3(MT / 128, DM / 128, 5), dim3(256), 0, stream>>>(
      xb, reb, Wqb,
      bq, bk, bv, bpk, bpq,
      Qb,
      MT, S2, DM, DM, DM, DM,
      (long long)DM * DM, (long long)MT * DM, (long long)S2 * DM,
      scale2, 0x11211, 3);

  // fully fused attention (flat grid, XCD-swizzled roles)
  attn_fused<<<dim3(1024), dim3(256), 0, stream>>>(
      Qb, Kb, VT, PKb, PQb, ctxb);

  // output projection: z0 only, fp32 out + bias, alpha=1
  gemm_bt<<<dim3(MT / 128, DM / 128, 1), dim3(256), 0, stream>>>(
      ctxb, ctxb, Wob,
      bo, bo, bo, bo, bo,
      d_out,
      MT, MT, DM, DM, DM, DM,
      0, 0, 0,
      1.0f, 0x0, 3);
}

// Round 12
// 258.979 us; speedup vs baseline: 1.4326x; 1.4326x over previous
//
#include <hip/hip_runtime.h>
#include <stdint.h>

typedef __attribute__((ext_vector_type(8))) short bf16x8;   // 8 bf16 in 4 VGPRs
typedef __attribute__((ext_vector_type(4))) float f32x4;

#define DM   1024
#define TT   1024
#define NH   16
#define DKH  64
#define SPAN 512
#define S2   1024   // 2*SPAN
#define MT   4096   // 4*TT rows

__device__ __forceinline__ unsigned short f2b(float f) {
  unsigned int u = __builtin_bit_cast(unsigned int, f);
  u = (u + 0x7FFFu + ((u >> 16) & 1u)) >> 16;   // RTNE
  return (unsigned short)u;
}
__device__ __forceinline__ float b2f(unsigned short h) {
  unsigned int u = ((unsigned int)h) << 16;
  return __builtin_bit_cast(float, u);
}

// XOR-swizzled LDS index for row-major [R][64]-short tiles (128 B rows).
// 16B chunks permuted within each row: phys_chunk = log_chunk ^ (row & 7).
__device__ __forceinline__ int swz(int row, int col) {
  return (row << 6) + ((((col >> 3) ^ (row & 7)) << 3) | (col & 7));
}

// async global->LDS 16B: LDS dest = wave-uniform base + lane*16 (linear);
// swizzle achieved by inverse-permuting the per-lane GLOBAL source column.
__device__ __forceinline__ void gl16(const void* g, void* l) {
  __builtin_amdgcn_global_load_lds(
      (const __attribute__((address_space(1))) unsigned int*)g,
      (__attribute__((address_space(3))) unsigned int*)l, 16, 0, 0);
}

// ---------------- batched f32 -> bf16 convert (one launch for all tensors) ----------------
struct CvtArgs {
  const float* src[8];
  unsigned short* dst[8];
  int n[8];
};
__global__ void cvt_multi(CvtArgs a) {
  const int ti = blockIdx.y;
  const float* __restrict__ in = a.src[ti];
  unsigned short* __restrict__ out = a.dst[ti];
  const int n = a.n[ti];
  int i = (blockIdx.x * blockDim.x + threadIdx.x) * 4;
  int stride = gridDim.x * blockDim.x * 4;
  for (; i < n; i += stride) {
    float4 v = *(const float4*)(in + i);
    ushort4 o;
    o.x = f2b(v.x); o.y = f2b(v.y); o.z = f2b(v.z); o.w = f2b(v.w);
    *(ushort4*)(out + i) = o;
  }
}

// ---------------- multi-z bf16 GEMM ----------------
// z < nzA: A = A0 (M0 rows, C at z*sC);  z >= nzA: A = A1 (M1 rows, C at nzA*sC + (z-nzA)*sC2)
// B (weights) contiguous at z*sB. alpha = a0 for z==0 or z==4, else 1.
// mode per z (4 bits in `modes`): 0 = f32 out, 1 = bf16 out, 2 = bf16 TRANSPOSED out C[col*Mz+row]
__global__ __launch_bounds__(256) void gemm_bt(
    const unsigned short* __restrict__ A0, const unsigned short* __restrict__ A1,
    const unsigned short* __restrict__ B,
    const float* __restrict__ bias0, const float* __restrict__ bias1,
    const float* __restrict__ bias2, const float* __restrict__ bias3,
    const float* __restrict__ bias4,
    void* __restrict__ C,
    int M0, int M1, int K, int lda, int ldb, int ldc,
    long long sB, long long sC, long long sC2,
    float a0, int modes, int nzA)
{
  __shared__ unsigned short Al[128 * 72];
  __shared__ unsigned short Bl[128 * 72];
  const int t = threadIdx.x;
  const int w = t >> 6, l = t & 63;
  const int g = l >> 4, li = l & 15;
  const int wr = w >> 1, wc = w & 1;
  const int row0 = blockIdx.x * 128, col0 = blockIdx.y * 128;
  const int z = blockIdx.z;
  const int Mz = (z < nzA) ? M0 : M1;
  if (row0 >= Mz) return;   // uniform early-exit for short (PK/PQ) slices
  const unsigned short* Ab = (z < nzA) ? A0 : A1;
  const unsigned short* Bb = B + (long long)z * sB;

  f32x4 acc[4][4];
#pragma unroll
  for (int m = 0; m < 4; m++)
#pragma unroll
    for (int n = 0; n < 4; n++) acc[m][n] = (f32x4){0.f, 0.f, 0.f, 0.f};

  for (int k0 = 0; k0 < K; k0 += 64) {
    __syncthreads();
#pragma unroll
    for (int i = 0; i < 4; i++) {
      int c = t + 256 * i;
      int r = c >> 3, c8 = (c & 7) * 8;
      *(bf16x8*)&Al[r * 72 + c8] = *(const bf16x8*)&Ab[(long long)(row0 + r) * lda + k0 + c8];
      *(bf16x8*)&Bl[r * 72 + c8] = *(const bf16x8*)&Bb[(long long)(col0 + r) * ldb + k0 + c8];
    }
    __syncthreads();
#pragma unroll
    for (int kk = 0; kk < 2; kk++) {
      bf16x8 af[4], bfr[4];
#pragma unroll
      for (int m = 0; m < 4; m++) af[m]  = *(bf16x8*)&Al[(wr * 64 + m * 16 + li) * 72 + kk * 32 + g * 8];
#pragma unroll
      for (int n = 0; n < 4; n++) bfr[n] = *(bf16x8*)&Bl[(wc * 64 + n * 16 + li) * 72 + kk * 32 + g * 8];
#pragma unroll
      for (int m = 0; m < 4; m++)
#pragma unroll
        for (int n = 0; n < 4; n++)
          acc[m][n] = __builtin_amdgcn_mfma_f32_16x16x32_bf16(af[m], bfr[n], acc[m][n], 0, 0, 0);
    }
  }

  const float alpha = (z == 0 || z == 4) ? a0 : 1.0f;
  const float* bias = z == 0 ? bias0 : (z == 1 ? bias1 : (z == 2 ? bias2 : (z == 3 ? bias3 : bias4)));
  const int mode = (modes >> (4 * z)) & 15;
  const long long zoff = (z < nzA) ? (long long)z * sC
                                   : (long long)nzA * sC + (long long)(z - nzA) * sC2;

#pragma unroll
  for (int m = 0; m < 4; m++) {
    int row = row0 + wr * 64 + m * 16 + g * 4;
#pragma unroll
    for (int n = 0; n < 4; n++) {
      int col = col0 + wc * 64 + n * 16 + li;
      float bv = bias ? bias[col] : 0.0f;
      if (mode == 2) {
        ushort4 st;
        st.x = f2b((acc[m][n][0] + bv) * alpha);
        st.y = f2b((acc[m][n][1] + bv) * alpha);
        st.z = f2b((acc[m][n][2] + bv) * alpha);
        st.w = f2b((acc[m][n][3] + bv) * alpha);
        *(ushort4*)&((unsigned short*)C)[zoff + (long long)col * Mz + row] = st;
      } else {
#pragma unroll
        for (int r = 0; r < 4; r++) {
          float v = (acc[m][n][r] + bv) * alpha;
          long long idx = zoff + (long long)(row + r) * ldc + col;
          if (mode == 1) ((unsigned short*)C)[idx] = f2b(v);
          else           ((float*)C)[idx] = v;
        }
      }
    }
  }
}

// ---------------- fully fused disentangled attention ----------------
// ROUND-10 VERBATIM (best verified: attn ~171 us, total 258 us).
// Round-11's precomputed gather-address arrays spilled to scratch (loop-carried
// 32-int live range; WRITE_SIZE 16->52 MB) and regressed — reverted.
// grid 1024 (flat, XCD-swizzled); block 256 (4 waves x 16 q-rows each).
// score'[q,k] = Qs.K + Qs.PK[s] + K.PQs[s], s = clamp(k-q+512, 0, 1023)
// (scale*log2e pre-folded into Q and PQ projections; softmax uses exp2)
// All LDS staging via global_load_lds (linear dest + inverse-swizzled per-lane
// global source column; read side keeps swz()).
// LDS 49152 B -> 3 blocks/CU:
//   Kl  [64][64]   K tile (shared); P tile after [D]
//   Vtl [64][64]   V^T tile, staged linearly from pre-transposed VT
//   Ct  [128][64]  persistent circular CtT[s&127][q] (raw PK in slide slots)
//   Pq  [128][64]  raw PQ window -> PtT[j][k] per tile
__global__ __launch_bounds__(256, 3) void attn_fused(
    const unsigned short* __restrict__ Qb, const unsigned short* __restrict__ Kb,
    const unsigned short* __restrict__ VT,
    const unsigned short* __restrict__ PKb, const unsigned short* __restrict__ PQb,
    unsigned short* __restrict__ ctxb)
{
  __shared__ unsigned short Kl[64 * 64];   // K tile; P tile after [D]
  __shared__ unsigned short Vtl[64 * 64];  // V^T tile
  __shared__ unsigned short Ct[128 * 64];  // circular CtT[s&127][q]
  __shared__ unsigned short Pq[128 * 64];  // raw PQ window -> PtT[j][k]

  const int t = threadIdx.x, w = t >> 6, l = t & 63, g = l >> 4, li = l & 15;
  const int lr = l >> 3;                   // lane's row-in-group (== row&7 in staging)
  const int sc8 = ((t & 7) ^ lr) * 8;      // inverse-swizzled source col (shorts)
  // XCD-aware role swizzle: each XCD gets 128 contiguous roles
  const int bid = blockIdx.x;
  const int role = (bid & 7) * 128 + (bid >> 3);
  const int q0 = (role & 15) * 64;
  const int h = (role >> 4) & 15;
  const int b = role >> 8;
  const long long qkbase = ((long long)b * TT) * DM + h * DKH;
  const long long vtb = (long long)(h * DKH) * MT + (long long)b * TT;  // + d*MT + k
  const int hbase = h * DKH;

  // Q fragments: direct global, once per block (loop-invariant)
  bf16x8 aq[2];
#pragma unroll
  for (int kk = 0; kk < 2; kk++)
    aq[kk] = *(const bf16x8*)&Qb[qkbase + (long long)(q0 + w * 16 + li) * DM + kk * 32 + g * 8];

  // ---- prologue: fill circular Ct for the kt=0 window ----
  int w0 = SPAN - q0 - 64;
  w0 = w0 < 0 ? 0 : (w0 > S2 - 128 ? S2 - 128 : w0);   // always a multiple of 64
#pragma unroll
  for (int i = 0; i < 4; i++) {
    const int wr0l = w * 8 + 32 * i;                   // logical row base 0..120
    const int jr = wr0l + lr;                          // this lane's logical row
    const int wr0 = (w0 + wr0l) & 127;                 // wrapped wave-uniform LDS row base
    gl16(&PKb[(long long)(w0 + jr) * DM + hbase + sc8], &Ct[wr0 * 64]);
  }
  __syncthreads();
  {
    f32x4 cp[8];
#pragma unroll
    for (int jb = 0; jb < 8; jb++) cp[jb] = (f32x4){0.f, 0.f, 0.f, 0.f};
    __builtin_amdgcn_s_setprio(1);
#pragma unroll
    for (int kk = 0; kk < 2; kk++)
#pragma unroll
      for (int jb = 0; jb < 8; jb++) {
        bf16x8 pkf = *(bf16x8*)&Ct[swz(jb * 16 + li, kk * 32 + g * 8)];
        cp[jb] = __builtin_amdgcn_mfma_f32_16x16x32_bf16(aq[kk], pkf, cp[jb], 0, 0, 0);
      }
    __builtin_amdgcn_s_setprio(0);
    __syncthreads();  // all raw reads done before overwrite
#pragma unroll
    for (int jb = 0; jb < 8; jb++) {
      ushort4 a;
      a.x = f2b(cp[jb][0]); a.y = f2b(cp[jb][1]);
      a.z = f2b(cp[jb][2]); a.w = f2b(cp[jb][3]);
      *(ushort4*)&Ct[swz(jb * 16 + li, w * 16 + g * 4)] = a;   // own-wave cols only
    }
  }

  f32x4 o[4];
#pragma unroll
  for (int n = 0; n < 4; n++) o[n] = (f32x4){0.f, 0.f, 0.f, 0.f};
  float mrow[4], lrow[4];
#pragma unroll
  for (int r = 0; r < 4; r++) { mrow[r] = -1e30f; lrow[r] = 0.f; }

  for (int kt = 0; kt < TT / 64; kt++) {
    const int k0 = kt * 64;
    const int d0 = k0 - q0 + SPAN;                       // block-uniform
    int w0n = d0 - 64;
    w0n = w0n < 0 ? 0 : (w0n > S2 - 128 ? S2 - 128 : w0n);
    const bool slide = (w0n != w0);                      // step is always exactly +64
    const int sb = w0 & 127;                             // slots replaced on slide (0 or 64)
    const int newrow0 = w0 + 128;                        // abs first new row on slide
    w0 = w0n;

    __syncthreads();  // [A] prev tile readers of Kl/Vtl/Ct/Pq done
    // stage K tile + V^T tile (global_load_lds, inverse-swizzled source)
#pragma unroll
    for (int i = 0; i < 2; i++) {
      const int wr0 = w * 8 + 32 * i;                    // wave-uniform LDS row base
      const int r = wr0 + lr;                            // lane's row
      gl16(&Kb[qkbase + (long long)(k0 + r) * DM + sc8], &Kl[wr0 * 64]);
      gl16(&VT[vtb + (long long)r * MT + k0 + sc8],      &Vtl[wr0 * 64]);
    }
    // stage raw PQ window (every tile; overwritten by PtT)
#pragma unroll
    for (int i = 0; i < 4; i++) {
      const int wr0 = w * 8 + 32 * i;                    // 0..120
      const int jr = wr0 + lr;
      gl16(&PQb[(long long)(w0 + jr) * DM + hbase + sc8], &Pq[wr0 * 64]);
    }
    // stage 64 new raw PK rows on slide (into recycled Ct slots)
    if (slide) {
#pragma unroll
      for (int i = 0; i < 2; i++) {
        const int wr0l = w * 8 + 32 * i;                 // 0..56
        const int jr = wr0l + lr;
        gl16(&PKb[(long long)(newrow0 + jr) * DM + hbase + sc8], &Ct[(sb + wr0l) * 64]);
      }
    }
    __syncthreads();  // [B] staging visible (vmcnt drained by barrier)

    // K strip A-fragments (for p2c)
    bf16x8 ak[2];
#pragma unroll
    for (int kk = 0; kk < 2; kk++) ak[kk] = *(bf16x8*)&Kl[swz(w * 16 + li, kk * 32 + g * 8)];

    __builtin_amdgcn_s_setprio(1);
    // QK^T: 16 q-rows x 64 k-cols (Q pre-scaled by scale*log2e)
    f32x4 sc[4];
#pragma unroll
    for (int f = 0; f < 4; f++) sc[f] = (f32x4){0.f, 0.f, 0.f, 0.f};
#pragma unroll
    for (int kk = 0; kk < 2; kk++)
#pragma unroll
      for (int f = 0; f < 4; f++) {
        bf16x8 bk = *(bf16x8*)&Kl[swz(f * 16 + li, kk * 32 + g * 8)];
        sc[f] = __builtin_amdgcn_mfma_f32_16x16x32_bf16(aq[kk], bk, sc[f], 0, 0, 0);
      }
    // c2p for the 64 new slots only (slide tiles)
    f32x4 cp2[4];
#pragma unroll
    for (int jb = 0; jb < 4; jb++) cp2[jb] = (f32x4){0.f, 0.f, 0.f, 0.f};
    if (slide) {
#pragma unroll
      for (int kk = 0; kk < 2; kk++)
#pragma unroll
        for (int jb = 0; jb < 4; jb++) {
          bf16x8 pkf = *(bf16x8*)&Ct[swz(sb + jb * 16 + li, kk * 32 + g * 8)];
          cp2[jb] = __builtin_amdgcn_mfma_f32_16x16x32_bf16(aq[kk], pkf, cp2[jb], 0, 0, 0);
        }
    }
    // p2c restricted to this wave's needed rows: s in [d0+16w-63, d0+16w+15]
    int loA = d0 + w * 16 - 63; loA = loA < w0 ? w0 : loA;
    int hiA = d0 + w * 16 + 15; hiA = hiA > w0 + 127 ? w0 + 127 : hiA;
    const int jb_lo = (loA - w0) >> 4;
    const int jb_n  = ((hiA - w0) >> 4) - jb_lo;   // 0..5 inclusive extra blocks
    f32x4 pp[6];
#pragma unroll
    for (int u = 0; u < 6; u++) pp[u] = (f32x4){0.f, 0.f, 0.f, 0.f};
#pragma unroll
    for (int kk = 0; kk < 2; kk++)
#pragma unroll
      for (int u = 0; u < 6; u++)
        if (u <= jb_n) {
          bf16x8 pqf = *(bf16x8*)&Pq[swz((jb_lo + u) * 16 + li, kk * 32 + g * 8)];
          pp[u] = __builtin_amdgcn_mfma_f32_16x16x32_bf16(ak[kk], pqf, pp[u], 0, 0, 0);
        }
    __builtin_amdgcn_s_setprio(0);
    __syncthreads();  // [C] all raw window reads + Kl fragment reads done

    // overwrite with transposed products (own-wave columns)
    if (slide) {
#pragma unroll
      for (int jb = 0; jb < 4; jb++) {
        ushort4 a;
        a.x = f2b(cp2[jb][0]); a.y = f2b(cp2[jb][1]);
        a.z = f2b(cp2[jb][2]); a.w = f2b(cp2[jb][3]);
        *(ushort4*)&Ct[swz(sb + jb * 16 + li, w * 16 + g * 4)] = a;
      }
    }
#pragma unroll
    for (int u = 0; u < 6; u++)
      if (u <= jb_n) {
        ushort4 a;
        a.x = f2b(pp[u][0]); a.y = f2b(pp[u][1]);
        a.z = f2b(pp[u][2]); a.w = f2b(pp[u][3]);
        *(ushort4*)&Pq[swz((jb_lo + u) * 16 + li, w * 16 + g * 4)] = a;
      }
    __syncthreads();  // [D] PtT visible cross-wave (Ct gather is wave-private)

    // combine + online softmax (base-2 domain)
    float p[4][4];
    float tmax[4] = {-1e30f, -1e30f, -1e30f, -1e30f};
#pragma unroll
    for (int f = 0; f < 4; f++)
#pragma unroll
      for (int r = 0; r < 4; r++) {
        int qi = w * 16 + g * 4 + r;
        int ki = f * 16 + li;
        int sraw = d0 + ki - qi;
        int scl = sraw < 0 ? 0 : (sraw > S2 - 1 ? S2 - 1 : sraw);
        int slot = scl & 127;
        int j = scl - w0;
        float v = sc[f][r] + b2f(Ct[swz(slot, qi)]) + b2f(Pq[swz(j, ki)]);
        p[f][r] = v;
        tmax[r] = fmaxf(tmax[r], v);
      }
#pragma unroll
    for (int msk = 1; msk <= 8; msk <<= 1)
#pragma unroll
      for (int r = 0; r < 4; r++) tmax[r] = fmaxf(tmax[r], __shfl_xor(tmax[r], msk));
    float corr[4];
#pragma unroll
    for (int r = 0; r < 4; r++) {
      float mn = fmaxf(mrow[r], tmax[r]);
      corr[r] = exp2f(mrow[r] - mn);
      mrow[r] = mn;
      lrow[r] *= corr[r];
    }
#pragma unroll
    for (int n = 0; n < 4; n++)
#pragma unroll
      for (int r = 0; r < 4; r++) o[n][r] *= corr[r];

    float ps[4] = {0.f, 0.f, 0.f, 0.f};
#pragma unroll
    for (int f = 0; f < 4; f++)
#pragma unroll
      for (int r = 0; r < 4; r++) {
        float e = exp2f(p[f][r] - mrow[r]);
        ps[r] += e;
        Kl[swz(w * 16 + g * 4 + r, f * 16 + li)] = f2b(e);  // P over Kl: own wave's rows
      }
#pragma unroll
    for (int msk = 1; msk <= 8; msk <<= 1)
#pragma unroll
      for (int r = 0; r < 4; r++) ps[r] += __shfl_xor(ps[r], msk);
#pragma unroll
    for (int r = 0; r < 4; r++) lrow[r] += ps[r];

    // PV: P rows wave-private (in-wave LDS ordering by compiler); V^T from LDS
    __builtin_amdgcn_s_setprio(1);
#pragma unroll
    for (int kk = 0; kk < 2; kk++) {
      bf16x8 ap = *(bf16x8*)&Kl[swz(w * 16 + li, kk * 32 + g * 8)];
#pragma unroll
      for (int n = 0; n < 4; n++) {
        bf16x8 bvf = *(bf16x8*)&Vtl[swz(n * 16 + li, kk * 32 + g * 8)];
        o[n] = __builtin_amdgcn_mfma_f32_16x16x32_bf16(ap, bvf, o[n], 0, 0, 0);
      }
    }
    __builtin_amdgcn_s_setprio(0);
  }

  // epilogue: ctx[b, q, h*64+d] bf16
#pragma unroll
  for (int n = 0; n < 4; n++)
#pragma unroll
    for (int r = 0; r < 4; r++) {
      int q = q0 + w * 16 + g * 4 + r;
      float val = o[n][r] / lrow[r];
      ctxb[((long long)b * TT + q) * DM + h * DKH + n * 16 + li] = f2b(val);
    }
}

// ---------------- host ----------------
extern "C" void kernel_launch(void* const* d_in, const int* in_sizes, int n_in,
                              void* d_out, int out_size, void* d_ws, size_t ws_size,
                              hipStream_t stream) {
  const float* x   = (const float*)d_in[0];
  const float* Wq  = (const float*)d_in[1];
  const float* bq  = (const float*)d_in[2];
  const float* Wk  = (const float*)d_in[3];
  const float* bk  = (const float*)d_in[4];
  const float* Wv  = (const float*)d_in[5];
  const float* bv  = (const float*)d_in[6];
  const float* Wo  = (const float*)d_in[7];
  const float* bo  = (const float*)d_in[8];
  const float* Wpk = (const float*)d_in[9];
  const float* bpk = (const float*)d_in[10];
  const float* Wpq = (const float*)d_in[11];
  const float* bpq = (const float*)d_in[12];
  const float* rel = (const float*)d_in[13];

  uint8_t* ws = (uint8_t*)d_ws;
  size_t off = 0;
  auto alloc = [&](size_t bytes) -> void* {
    void* p = ws + off;
    off += (bytes + 255) & ~(size_t)255;
    return p;
  };
  // Weight order Wq,Wk,Wv,Wpk,Wpq MUST be contiguous (z-strided B in the fused launch);
  // Qb,Kb,VT,PKb,PQb MUST be contiguous (z-strided C). All sizes are 256-multiples.
  unsigned short* xb   = (unsigned short*)alloc((size_t)MT * DM * 2);
  unsigned short* Wqb  = (unsigned short*)alloc((size_t)DM * DM * 2);
  unsigned short* Wkb  = (unsigned short*)alloc((size_t)DM * DM * 2);
  unsigned short* Wvb  = (unsigned short*)alloc((size_t)DM * DM * 2);
  unsigned short* Wpkb = (unsigned short*)alloc((size_t)DM * DM * 2);
  unsigned short* Wpqb = (unsigned short*)alloc((size_t)DM * DM * 2);
  unsigned short* Wob  = (unsigned short*)alloc((size_t)DM * DM * 2);
  unsigned short* reb  = (unsigned short*)alloc((size_t)S2 * DM * 2);
  unsigned short* Qb   = (unsigned short*)alloc((size_t)MT * DM * 2);
  unsigned short* Kb   = (unsigned short*)alloc((size_t)MT * DM * 2);
  unsigned short* VT   = (unsigned short*)alloc((size_t)MT * DM * 2);  // V^T: [h*64+d][b*1024+k]
  unsigned short* PKb  = (unsigned short*)alloc((size_t)S2 * DM * 2);
  unsigned short* PQb  = (unsigned short*)alloc((size_t)S2 * DM * 2);
  unsigned short* ctxb = (unsigned short*)alloc((size_t)MT * DM * 2);

  // scale * log2(e): softmax runs in base-2 domain (exp2f)
  const float scale2 = 0.07216878364870323f * 1.4426950408889634f;

  // one batched convert launch for all 8 fp32 tensors
  CvtArgs ca;
  ca.src[0] = x;   ca.dst[0] = xb;   ca.n[0] = MT * DM;
  ca.src[1] = Wq;  ca.dst[1] = Wqb;  ca.n[1] = DM * DM;
  ca.src[2] = Wk;  ca.dst[2] = Wkb;  ca.n[2] = DM * DM;
  ca.src[3] = Wv;  ca.dst[3] = Wvb;  ca.n[3] = DM * DM;
  ca.src[4] = Wpk; ca.dst[4] = Wpkb; ca.n[4] = DM * DM;
  ca.src[5] = Wpq; ca.dst[5] = Wpqb; ca.n[5] = DM * DM;
  ca.src[6] = Wo;  ca.dst[6] = Wob;  ca.n[6] = DM * DM;
  ca.src[7] = rel; ca.dst[7] = reb;  ca.n[7] = S2 * DM;
  cvt_multi<<<dim3(1024, 8), dim3(256), 0, stream>>>(ca);

  // ALL FIVE projections in one launch:
  //   z0=Q (A=xb, alpha=scale2, bf16), z1=K (bf16), z2=V (bf16 transposed -> VT),
  //   z3=PK (A=reb, alpha=1, bf16), z4=PQ (A=reb, alpha=scale2, bf16)
  gemm_bt<<<dim3(MT / 128, DM / 128, 5), dim3(256), 0, stream>>>(
      xb, reb, Wqb,
      bq, bk, bv, bpk, bpq,
      Qb,
      MT, S2, DM, DM, DM, DM,
      (long long)DM * DM, (long long)MT * DM, (long long)S2 * DM,
      scale2, 0x11211, 3);

  // fully fused attention (flat grid, XCD-swizzled roles)
  attn_fused<<<dim3(1024), dim3(256), 0, stream>>>(
      Qb, Kb, VT, PKb, PQb, ctxb);

  // output projection: z0 only, fp32 out + bias, alpha=1
  gemm_bt<<<dim3(MT / 128, DM / 128, 1), dim3(256), 0, stream>>>(
      ctxb, ctxb, Wob,
      bo, bo, bo, bo, bo,
      d_out,
      MT, MT, DM, DM, DM, DM,
      0, 0, 0,
      1.0f, 0x0, 3);
}

// Round 13
// 250.952 us; speedup vs baseline: 1.4784x; 1.0320x over previous
//
#include <hip/hip_runtime.h>
#include <stdint.h>

typedef __attribute__((ext_vector_type(8))) short bf16x8;   // 8 bf16 in 4 VGPRs
typedef __attribute__((ext_vector_type(4))) float f32x4;

#define DM   1024
#define TT   1024
#define NH   16
#define DKH  64
#define SPAN 512
#define S2   1024   // 2*SPAN
#define MT   4096   // 4*TT rows

__device__ __forceinline__ unsigned short f2b(float f) {
  unsigned int u = __builtin_bit_cast(unsigned int, f);
  u = (u + 0x7FFFu + ((u >> 16) & 1u)) >> 16;   // RTNE
  return (unsigned short)u;
}
__device__ __forceinline__ float b2f(unsigned short h) {
  unsigned int u = ((unsigned int)h) << 16;
  return __builtin_bit_cast(float, u);
}

// XOR-swizzled LDS index for row-major [R][64]-short tiles (128 B rows).
// 16B chunks permuted within each row: phys_chunk = log_chunk ^ (row & 7).
__device__ __forceinline__ int swz(int row, int col) {
  return (row << 6) + ((((col >> 3) ^ (row & 7)) << 3) | (col & 7));
}

// async global->LDS 16B: LDS dest = wave-uniform base + lane*16 (linear);
// swizzle achieved by inverse-permuting the per-lane GLOBAL source column.
__device__ __forceinline__ void gl16(const void* g, void* l) {
  __builtin_amdgcn_global_load_lds(
      (const __attribute__((address_space(1))) unsigned int*)g,
      (__attribute__((address_space(3))) unsigned int*)l, 16, 0, 0);
}

// ---------------- batched f32 -> bf16 convert (one launch for all tensors) ----------------
struct CvtArgs {
  const float* src[8];
  unsigned short* dst[8];
  int n[8];
};
__global__ void cvt_multi(CvtArgs a) {
  const int ti = blockIdx.y;
  const float* __restrict__ in = a.src[ti];
  unsigned short* __restrict__ out = a.dst[ti];
  const int n = a.n[ti];
  int i = (blockIdx.x * blockDim.x + threadIdx.x) * 4;
  int stride = gridDim.x * blockDim.x * 4;
  for (; i < n; i += stride) {
    float4 v = *(const float4*)(in + i);
    ushort4 o;
    o.x = f2b(v.x); o.y = f2b(v.y); o.z = f2b(v.z); o.w = f2b(v.w);
    *(ushort4*)(out + i) = o;
  }
}

// ---------------- multi-z bf16 GEMM ----------------
// z < nzA: A = A0 (M0 rows, C at z*sC);  z >= nzA: A = A1 (M1 rows, C at nzA*sC + (z-nzA)*sC2)
// B (weights) contiguous at z*sB. alpha = a0 for z==0 or z==4, else 1.
// mode per z (4 bits in `modes`): 0 = f32 out, 1 = bf16 out, 2 = bf16 TRANSPOSED out C[col*Mz+row]
// Staging uses global_load_lds (r10-verified pattern): stride-64 LDS, linear dest,
// inverse-swizzled per-lane global source column, swz() fragment reads.
__global__ __launch_bounds__(256) void gemm_bt(
    const unsigned short* __restrict__ A0, const unsigned short* __restrict__ A1,
    const unsigned short* __restrict__ B,
    const float* __restrict__ bias0, const float* __restrict__ bias1,
    const float* __restrict__ bias2, const float* __restrict__ bias3,
    const float* __restrict__ bias4,
    void* __restrict__ C,
    int M0, int M1, int K, int lda, int ldb, int ldc,
    long long sB, long long sC, long long sC2,
    float a0, int modes, int nzA)
{
  __shared__ unsigned short Al[128 * 64];
  __shared__ unsigned short Bl[128 * 64];
  const int t = threadIdx.x;
  const int w = t >> 6, l = t & 63;
  const int g = l >> 4, li = l & 15;
  const int wr = w >> 1, wc = w & 1;
  const int lr = l >> 3;                   // lane's row-in-group (== row&7 in staging)
  const int sc8 = ((t & 7) ^ lr) * 8;      // inverse-swizzled source col (shorts)
  const int row0 = blockIdx.x * 128, col0 = blockIdx.y * 128;
  const int z = blockIdx.z;
  const int Mz = (z < nzA) ? M0 : M1;
  if (row0 >= Mz) return;   // uniform early-exit for short (PK/PQ) slices
  const unsigned short* Ab = (z < nzA) ? A0 : A1;
  const unsigned short* Bb = B + (long long)z * sB;

  f32x4 acc[4][4];
#pragma unroll
  for (int m = 0; m < 4; m++)
#pragma unroll
    for (int n = 0; n < 4; n++) acc[m][n] = (f32x4){0.f, 0.f, 0.f, 0.f};

  for (int k0 = 0; k0 < K; k0 += 64) {
    __syncthreads();
#pragma unroll
    for (int i = 0; i < 4; i++) {
      const int wr0 = w * 8 + 32 * i;                    // wave-uniform LDS row base 0..120
      const int r = wr0 + lr;                            // lane's row
      gl16(&Ab[(long long)(row0 + r) * lda + k0 + sc8], &Al[wr0 * 64]);
      gl16(&Bb[(long long)(col0 + r) * ldb + k0 + sc8], &Bl[wr0 * 64]);
    }
    __syncthreads();
#pragma unroll
    for (int kk = 0; kk < 2; kk++) {
      bf16x8 af[4], bfr[4];
#pragma unroll
      for (int m = 0; m < 4; m++) af[m]  = *(bf16x8*)&Al[swz(wr * 64 + m * 16 + li, kk * 32 + g * 8)];
#pragma unroll
      for (int n = 0; n < 4; n++) bfr[n] = *(bf16x8*)&Bl[swz(wc * 64 + n * 16 + li, kk * 32 + g * 8)];
#pragma unroll
      for (int m = 0; m < 4; m++)
#pragma unroll
        for (int n = 0; n < 4; n++)
          acc[m][n] = __builtin_amdgcn_mfma_f32_16x16x32_bf16(af[m], bfr[n], acc[m][n], 0, 0, 0);
    }
  }

  const float alpha = (z == 0 || z == 4) ? a0 : 1.0f;
  const float* bias = z == 0 ? bias0 : (z == 1 ? bias1 : (z == 2 ? bias2 : (z == 3 ? bias3 : bias4)));
  const int mode = (modes >> (4 * z)) & 15;
  const long long zoff = (z < nzA) ? (long long)z * sC
                                   : (long long)nzA * sC + (long long)(z - nzA) * sC2;

#pragma unroll
  for (int m = 0; m < 4; m++) {
    int row = row0 + wr * 64 + m * 16 + g * 4;
#pragma unroll
    for (int n = 0; n < 4; n++) {
      int col = col0 + wc * 64 + n * 16 + li;
      float bv = bias ? bias[col] : 0.0f;
      if (mode == 2) {
        ushort4 st;
        st.x = f2b((acc[m][n][0] + bv) * alpha);
        st.y = f2b((acc[m][n][1] + bv) * alpha);
        st.z = f2b((acc[m][n][2] + bv) * alpha);
        st.w = f2b((acc[m][n][3] + bv) * alpha);
        *(ushort4*)&((unsigned short*)C)[zoff + (long long)col * Mz + row] = st;
      } else {
#pragma unroll
        for (int r = 0; r < 4; r++) {
          float v = (acc[m][n][r] + bv) * alpha;
          long long idx = zoff + (long long)(row + r) * ldc + col;
          if (mode == 1) ((unsigned short*)C)[idx] = f2b(v);
          else           ((float*)C)[idx] = v;
        }
      }
    }
  }
}

// ---------------- fully fused disentangled attention ----------------
// ROUND-12 VERBATIM (best verified: attn ~174 us, total 259 us).
// grid 1024 (flat, XCD-swizzled); block 256 (4 waves x 16 q-rows each).
// score'[q,k] = Qs.K + Qs.PK[s] + K.PQs[s], s = clamp(k-q+512, 0, 1023)
// (scale*log2e pre-folded into Q and PQ projections; softmax uses exp2)
// All LDS staging via global_load_lds (linear dest + inverse-swizzled per-lane
// global source column; read side keeps swz()).
// LDS 49152 B -> 3 blocks/CU:
//   Kl  [64][64]   K tile (shared); P tile after [D]
//   Vtl [64][64]   V^T tile, staged linearly from pre-transposed VT
//   Ct  [128][64]  persistent circular CtT[s&127][q] (raw PK in slide slots)
//   Pq  [128][64]  raw PQ window -> PtT[j][k] per tile
__global__ __launch_bounds__(256, 3) void attn_fused(
    const unsigned short* __restrict__ Qb, const unsigned short* __restrict__ Kb,
    const unsigned short* __restrict__ VT,
    const unsigned short* __restrict__ PKb, const unsigned short* __restrict__ PQb,
    unsigned short* __restrict__ ctxb)
{
  __shared__ unsigned short Kl[64 * 64];   // K tile; P tile after [D]
  __shared__ unsigned short Vtl[64 * 64];  // V^T tile
  __shared__ unsigned short Ct[128 * 64];  // circular CtT[s&127][q]
  __shared__ unsigned short Pq[128 * 64];  // raw PQ window -> PtT[j][k]

  const int t = threadIdx.x, w = t >> 6, l = t & 63, g = l >> 4, li = l & 15;
  const int lr = l >> 3;                   // lane's row-in-group (== row&7 in staging)
  const int sc8 = ((t & 7) ^ lr) * 8;      // inverse-swizzled source col (shorts)
  // XCD-aware role swizzle: each XCD gets 128 contiguous roles
  const int bid = blockIdx.x;
  const int role = (bid & 7) * 128 + (bid >> 3);
  const int q0 = (role & 15) * 64;
  const int h = (role >> 4) & 15;
  const int b = role >> 8;
  const long long qkbase = ((long long)b * TT) * DM + h * DKH;
  const long long vtb = (long long)(h * DKH) * MT + (long long)b * TT;  // + d*MT + k
  const int hbase = h * DKH;

  // Q fragments: direct global, once per block (loop-invariant)
  bf16x8 aq[2];
#pragma unroll
  for (int kk = 0; kk < 2; kk++)
    aq[kk] = *(const bf16x8*)&Qb[qkbase + (long long)(q0 + w * 16 + li) * DM + kk * 32 + g * 8];

  // ---- prologue: fill circular Ct for the kt=0 window ----
  int w0 = SPAN - q0 - 64;
  w0 = w0 < 0 ? 0 : (w0 > S2 - 128 ? S2 - 128 : w0);   // always a multiple of 64
#pragma unroll
  for (int i = 0; i < 4; i++) {
    const int wr0l = w * 8 + 32 * i;                   // logical row base 0..120
    const int jr = wr0l + lr;                          // this lane's logical row
    const int wr0 = (w0 + wr0l) & 127;                 // wrapped wave-uniform LDS row base
    gl16(&PKb[(long long)(w0 + jr) * DM + hbase + sc8], &Ct[wr0 * 64]);
  }
  __syncthreads();
  {
    f32x4 cp[8];
#pragma unroll
    for (int jb = 0; jb < 8; jb++) cp[jb] = (f32x4){0.f, 0.f, 0.f, 0.f};
    __builtin_amdgcn_s_setprio(1);
#pragma unroll
    for (int kk = 0; kk < 2; kk++)
#pragma unroll
      for (int jb = 0; jb < 8; jb++) {
        bf16x8 pkf = *(bf16x8*)&Ct[swz(jb * 16 + li, kk * 32 + g * 8)];
        cp[jb] = __builtin_amdgcn_mfma_f32_16x16x32_bf16(aq[kk], pkf, cp[jb], 0, 0, 0);
      }
    __builtin_amdgcn_s_setprio(0);
    __syncthreads();  // all raw reads done before overwrite
#pragma unroll
    for (int jb = 0; jb < 8; jb++) {
      ushort4 a;
      a.x = f2b(cp[jb][0]); a.y = f2b(cp[jb][1]);
      a.z = f2b(cp[jb][2]); a.w = f2b(cp[jb][3]);
      *(ushort4*)&Ct[swz(jb * 16 + li, w * 16 + g * 4)] = a;   // own-wave cols only
    }
  }

  f32x4 o[4];
#pragma unroll
  for (int n = 0; n < 4; n++) o[n] = (f32x4){0.f, 0.f, 0.f, 0.f};
  float mrow[4], lrow[4];
#pragma unroll
  for (int r = 0; r < 4; r++) { mrow[r] = -1e30f; lrow[r] = 0.f; }

  for (int kt = 0; kt < TT / 64; kt++) {
    const int k0 = kt * 64;
    const int d0 = k0 - q0 + SPAN;                       // block-uniform
    int w0n = d0 - 64;
    w0n = w0n < 0 ? 0 : (w0n > S2 - 128 ? S2 - 128 : w0n);
    const bool slide = (w0n != w0);                      // step is always exactly +64
    const int sb = w0 & 127;                             // slots replaced on slide (0 or 64)
    const int newrow0 = w0 + 128;                        // abs first new row on slide
    w0 = w0n;

    __syncthreads();  // [A] prev tile readers of Kl/Vtl/Ct/Pq done
    // stage K tile + V^T tile (global_load_lds, inverse-swizzled source)
#pragma unroll
    for (int i = 0; i < 2; i++) {
      const int wr0 = w * 8 + 32 * i;                    // wave-uniform LDS row base
      const int r = wr0 + lr;                            // lane's row
      gl16(&Kb[qkbase + (long long)(k0 + r) * DM + sc8], &Kl[wr0 * 64]);
      gl16(&VT[vtb + (long long)r * MT + k0 + sc8],      &Vtl[wr0 * 64]);
    }
    // stage raw PQ window (every tile; overwritten by PtT)
#pragma unroll
    for (int i = 0; i < 4; i++) {
      const int wr0 = w * 8 + 32 * i;                    // 0..120
      const int jr = wr0 + lr;
      gl16(&PQb[(long long)(w0 + jr) * DM + hbase + sc8], &Pq[wr0 * 64]);
    }
    // stage 64 new raw PK rows on slide (into recycled Ct slots)
    if (slide) {
#pragma unroll
      for (int i = 0; i < 2; i++) {
        const int wr0l = w * 8 + 32 * i;                 // 0..56
        const int jr = wr0l + lr;
        gl16(&PKb[(long long)(newrow0 + jr) * DM + hbase + sc8], &Ct[(sb + wr0l) * 64]);
      }
    }
    __syncthreads();  // [B] staging visible (vmcnt drained by barrier)

    // K strip A-fragments (for p2c)
    bf16x8 ak[2];
#pragma unroll
    for (int kk = 0; kk < 2; kk++) ak[kk] = *(bf16x8*)&Kl[swz(w * 16 + li, kk * 32 + g * 8)];

    __builtin_amdgcn_s_setprio(1);
    // QK^T: 16 q-rows x 64 k-cols (Q pre-scaled by scale*log2e)
    f32x4 sc[4];
#pragma unroll
    for (int f = 0; f < 4; f++) sc[f] = (f32x4){0.f, 0.f, 0.f, 0.f};
#pragma unroll
    for (int kk = 0; kk < 2; kk++)
#pragma unroll
      for (int f = 0; f < 4; f++) {
        bf16x8 bk = *(bf16x8*)&Kl[swz(f * 16 + li, kk * 32 + g * 8)];
        sc[f] = __builtin_amdgcn_mfma_f32_16x16x32_bf16(aq[kk], bk, sc[f], 0, 0, 0);
      }
    // c2p for the 64 new slots only (slide tiles)
    f32x4 cp2[4];
#pragma unroll
    for (int jb = 0; jb < 4; jb++) cp2[jb] = (f32x4){0.f, 0.f, 0.f, 0.f};
    if (slide) {
#pragma unroll
      for (int kk = 0; kk < 2; kk++)
#pragma unroll
        for (int jb = 0; jb < 4; jb++) {
          bf16x8 pkf = *(bf16x8*)&Ct[swz(sb + jb * 16 + li, kk * 32 + g * 8)];
          cp2[jb] = __builtin_amdgcn_mfma_f32_16x16x32_bf16(aq[kk], pkf, cp2[jb], 0, 0, 0);
        }
    }
    // p2c restricted to this wave's needed rows: s in [d0+16w-63, d0+16w+15]
    int loA = d0 + w * 16 - 63; loA = loA < w0 ? w0 : loA;
    int hiA = d0 + w * 16 + 15; hiA = hiA > w0 + 127 ? w0 + 127 : hiA;
    const int jb_lo = (loA - w0) >> 4;
    const int jb_n  = ((hiA - w0) >> 4) - jb_lo;   // 0..5 inclusive extra blocks
    f32x4 pp[6];
#pragma unroll
    for (int u = 0; u < 6; u++) pp[u] = (f32x4){0.f, 0.f, 0.f, 0.f};
#pragma unroll
    for (int kk = 0; kk < 2; kk++)
#pragma unroll
      for (int u = 0; u < 6; u++)
        if (u <= jb_n) {
          bf16x8 pqf = *(bf16x8*)&Pq[swz((jb_lo + u) * 16 + li, kk * 32 + g * 8)];
          pp[u] = __builtin_amdgcn_mfma_f32_16x16x32_bf16(ak[kk], pqf, pp[u], 0, 0, 0);
        }
    __builtin_amdgcn_s_setprio(0);
    __syncthreads();  // [C] all raw window reads + Kl fragment reads done

    // overwrite with transposed products (own-wave columns)
    if (slide) {
#pragma unroll
      for (int jb = 0; jb < 4; jb++) {
        ushort4 a;
        a.x = f2b(cp2[jb][0]); a.y = f2b(cp2[jb][1]);
        a.z = f2b(cp2[jb][2]); a.w = f2b(cp2[jb][3]);
        *(ushort4*)&Ct[swz(sb + jb * 16 + li, w * 16 + g * 4)] = a;
      }
    }
#pragma unroll
    for (int u = 0; u < 6; u++)
      if (u <= jb_n) {
        ushort4 a;
        a.x = f2b(pp[u][0]); a.y = f2b(pp[u][1]);
        a.z = f2b(pp[u][2]); a.w = f2b(pp[u][3]);
        *(ushort4*)&Pq[swz((jb_lo + u) * 16 + li, w * 16 + g * 4)] = a;
      }
    __syncthreads();  // [D] PtT visible cross-wave (Ct gather is wave-private)

    // combine + online softmax (base-2 domain)
    float p[4][4];
    float tmax[4] = {-1e30f, -1e30f, -1e30f, -1e30f};
#pragma unroll
    for (int f = 0; f < 4; f++)
#pragma unroll
      for (int r = 0; r < 4; r++) {
        int qi = w * 16 + g * 4 + r;
        int ki = f * 16 + li;
        int sraw = d0 + ki - qi;
        int scl = sraw < 0 ? 0 : (sraw > S2 - 1 ? S2 - 1 : sraw);
        int slot = scl & 127;
        int j = scl - w0;
        float v = sc[f][r] + b2f(Ct[swz(slot, qi)]) + b2f(Pq[swz(j, ki)]);
        p[f][r] = v;
        tmax[r] = fmaxf(tmax[r], v);
      }
#pragma unroll
    for (int msk = 1; msk <= 8; msk <<= 1)
#pragma unroll
      for (int r = 0; r < 4; r++) tmax[r] = fmaxf(tmax[r], __shfl_xor(tmax[r], msk));
    float corr[4];
#pragma unroll
    for (int r = 0; r < 4; r++) {
      float mn = fmaxf(mrow[r], tmax[r]);
      corr[r] = exp2f(mrow[r] - mn);
      mrow[r] = mn;
      lrow[r] *= corr[r];
    }
#pragma unroll
    for (int n = 0; n < 4; n++)
#pragma unroll
      for (int r = 0; r < 4; r++) o[n][r] *= corr[r];

    float ps[4] = {0.f, 0.f, 0.f, 0.f};
#pragma unroll
    for (int f = 0; f < 4; f++)
#pragma unroll
      for (int r = 0; r < 4; r++) {
        float e = exp2f(p[f][r] - mrow[r]);
        ps[r] += e;
        Kl[swz(w * 16 + g * 4 + r, f * 16 + li)] = f2b(e);  // P over Kl: own wave's rows
      }
#pragma unroll
    for (int msk = 1; msk <= 8; msk <<= 1)
#pragma unroll
      for (int r = 0; r < 4; r++) ps[r] += __shfl_xor(ps[r], msk);
#pragma unroll
    for (int r = 0; r < 4; r++) lrow[r] += ps[r];

    // PV: P rows wave-private (in-wave LDS ordering by compiler); V^T from LDS
    __builtin_amdgcn_s_setprio(1);
#pragma unroll
    for (int kk = 0; kk < 2; kk++) {
      bf16x8 ap = *(bf16x8*)&Kl[swz(w * 16 + li, kk * 32 + g * 8)];
#pragma unroll
      for (int n = 0; n < 4; n++) {
        bf16x8 bvf = *(bf16x8*)&Vtl[swz(n * 16 + li, kk * 32 + g * 8)];
        o[n] = __builtin_amdgcn_mfma_f32_16x16x32_bf16(ap, bvf, o[n], 0, 0, 0);
      }
    }
    __builtin_amdgcn_s_setprio(0);
  }

  // epilogue: ctx[b, q, h*64+d] bf16
#pragma unroll
  for (int n = 0; n < 4; n++)
#pragma unroll
    for (int r = 0; r < 4; r++) {
      int q = q0 + w * 16 + g * 4 + r;
      float val = o[n][r] / lrow[r];
      ctxb[((long long)b * TT + q) * DM + h * DKH + n * 16 + li] = f2b(val);
    }
}

// ---------------- host ----------------
extern "C" void kernel_launch(void* const* d_in, const int* in_sizes, int n_in,
                              void* d_out, int out_size, void* d_ws, size_t ws_size,
                              hipStream_t stream) {
  const float* x   = (const float*)d_in[0];
  const float* Wq  = (const float*)d_in[1];
  const float* bq  = (const float*)d_in[2];
  const float* Wk  = (const float*)d_in[3];
  const float* bk  = (const float*)d_in[4];
  const float* Wv  = (const float*)d_in[5];
  const float* bv  = (const float*)d_in[6];
  const float* Wo  = (const float*)d_in[7];
  const float* bo  = (const float*)d_in[8];
  const float* Wpk = (const float*)d_in[9];
  const float* bpk = (const float*)d_in[10];
  const float* Wpq = (const float*)d_in[11];
  const float* bpq = (const float*)d_in[12];
  const float* rel = (const float*)d_in[13];

  uint8_t* ws = (uint8_t*)d_ws;
  size_t off = 0;
  auto alloc = [&](size_t bytes) -> void* {
    void* p = ws + off;
    off += (bytes + 255) & ~(size_t)255;
    return p;
  };
  // Weight order Wq,Wk,Wv,Wpk,Wpq MUST be contiguous (z-strided B in the fused launch);
  // Qb,Kb,VT,PKb,PQb MUST be contiguous (z-strided C). All sizes are 256-multiples.
  unsigned short* xb   = (unsigned short*)alloc((size_t)MT * DM * 2);
  unsigned short* Wqb  = (unsigned short*)alloc((size_t)DM * DM * 2);
  unsigned short* Wkb  = (unsigned short*)alloc((size_t)DM * DM * 2);
  unsigned short* Wvb  = (unsigned short*)alloc((size_t)DM * DM * 2);
  unsigned short* Wpkb = (unsigned short*)alloc((size_t)DM * DM * 2);
  unsigned short* Wpqb = (unsigned short*)alloc((size_t)DM * DM * 2);
  unsigned short* Wob  = (unsigned short*)alloc((size_t)DM * DM * 2);
  unsigned short* reb  = (unsigned short*)alloc((size_t)S2 * DM * 2);
  unsigned short* Qb   = (unsigned short*)alloc((size_t)MT * DM * 2);
  unsigned short* Kb   = (unsigned short*)alloc((size_t)MT * DM * 2);
  unsigned short* VT   = (unsigned short*)alloc((size_t)MT * DM * 2);  // V^T: [h*64+d][b*1024+k]
  unsigned short* PKb  = (unsigned short*)alloc((size_t)S2 * DM * 2);
  unsigned short* PQb  = (unsigned short*)alloc((size_t)S2 * DM * 2);
  unsigned short* ctxb = (unsigned short*)alloc((size_t)MT * DM * 2);

  // scale * log2(e): softmax runs in base-2 domain (exp2f)
  const float scale2 = 0.07216878364870323f * 1.4426950408889634f;

  // one batched convert launch for all 8 fp32 tensors
  CvtArgs ca;
  ca.src[0] = x;   ca.dst[0] = xb;   ca.n[0] = MT * DM;
  ca.src[1] = Wq;  ca.dst[1] = Wqb;  ca.n[1] = DM * DM;
  ca.src[2] = Wk;  ca.dst[2] = Wkb;  ca.n[2] = DM * DM;
  ca.src[3] = Wv;  ca.dst[3] = Wvb;  ca.n[3] = DM * DM;
  ca.src[4] = Wpk; ca.dst[4] = Wpkb; ca.n[4] = DM * DM;
  ca.src[5] = Wpq; ca.dst[5] = Wpqb; ca.n[5] = DM * DM;
  ca.src[6] = Wo;  ca.dst[6] = Wob;  ca.n[6] = DM * DM;
  ca.src[7] = rel; ca.dst[7] = reb;  ca.n[7] = S2 * DM;
  cvt_multi<<<dim3(1024, 8), dim3(256), 0, stream>>>(ca);

  // ALL FIVE projections in one launch:
  //   z0=Q (A=xb, alpha=scale2, bf16), z1=K (bf16), z2=V (bf16 transposed -> VT),
  //   z3=PK (A=reb, alpha=1, bf16), z4=PQ (A=reb, alpha=scale2, bf16)
  gemm_bt<<<dim3(MT / 128, DM / 128, 5), dim3(256), 0, stream>>>(
      xb, reb, Wqb,
      bq, bk, bv, bpk, bpq,
      Qb,
      MT, S2, DM, DM, DM, DM,
      (long long)DM * DM, (long long)MT * DM, (long long)S2 * DM,
      scale2, 0x11211, 3);

  // fully fused attention (flat grid, XCD-swizzled roles)
  attn_fused<<<dim3(1024), dim3(256), 0, stream>>>(
      Qb, Kb, VT, PKb, PQb, ctxb);

  // output projection: z0 only, fp32 out + bias, alpha=1
  gemm_bt<<<dim3(MT / 128, DM / 128, 1), dim3(256), 0, stream>>>(
      ctxb, ctxb, Wob,
      bo, bo, bo, bo, bo,
      d_out,
      MT, MT, DM, DM, DM, DM,
      0, 0, 0,
      1.0f, 0x0, 3);
}

// Round 14
// 247.888 us; speedup vs baseline: 1.4967x; 1.0124x over previous
//
#include <hip/hip_runtime.h>
#include <stdint.h>

typedef __attribute__((ext_vector_type(8))) short bf16x8;   // 8 bf16 in 4 VGPRs
typedef __attribute__((ext_vector_type(4))) float f32x4;

#define DM   1024
#define TT   1024
#define NH   16
#define DKH  64
#define SPAN 512
#define S2   1024   // 2*SPAN
#define MT   4096   // 4*TT rows

__device__ __forceinline__ unsigned short f2b(float f) {
  unsigned int u = __builtin_bit_cast(unsigned int, f);
  u = (u + 0x7FFFu + ((u >> 16) & 1u)) >> 16;   // RTNE
  return (unsigned short)u;
}
__device__ __forceinline__ float b2f(unsigned short h) {
  unsigned int u = ((unsigned int)h) << 16;
  return __builtin_bit_cast(float, u);
}

// XOR-swizzled LDS index for row-major [R][64]-short tiles (128 B rows).
// 16B chunks permuted within each row: phys_chunk = log_chunk ^ (row & 7).
__device__ __forceinline__ int swz(int row, int col) {
  return (row << 6) + ((((col >> 3) ^ (row & 7)) << 3) | (col & 7));
}

// async global->LDS 16B: LDS dest = wave-uniform base + lane*16 (linear);
// swizzle achieved by inverse-permuting the per-lane GLOBAL source column.
__device__ __forceinline__ void gl16(const void* g, void* l) {
  __builtin_amdgcn_global_load_lds(
      (const __attribute__((address_space(1))) unsigned int*)g,
      (__attribute__((address_space(3))) unsigned int*)l, 16, 0, 0);
}

// ---------------- batched f32 -> bf16 convert (one launch for all tensors) ----------------
struct CvtArgs {
  const float* src[8];
  unsigned short* dst[8];
  int n[8];
};
__global__ void cvt_multi(CvtArgs a) {
  const int ti = blockIdx.y;
  const float* __restrict__ in = a.src[ti];
  unsigned short* __restrict__ out = a.dst[ti];
  const int n = a.n[ti];
  int i = (blockIdx.x * blockDim.x + threadIdx.x) * 4;
  int stride = gridDim.x * blockDim.x * 4;
  for (; i < n; i += stride) {
    float4 v = *(const float4*)(in + i);
    ushort4 o;
    o.x = f2b(v.x); o.y = f2b(v.y); o.z = f2b(v.z); o.w = f2b(v.w);
    *(ushort4*)(out + i) = o;
  }
}

// ---------------- multi-z bf16 GEMM ----------------
// z < nzA: A = A0 (M0 rows, C at z*sC);  z >= nzA: A = A1 (M1 rows, C at nzA*sC + (z-nzA)*sC2)
// B (weights) contiguous at z*sB. alpha = a0 for z==0 or z==4, else 1.
// mode per z (4 bits in `modes`): 0 = f32 out, 1 = bf16 out, 2 = bf16 TRANSPOSED out C[col*Mz+row]
// Staging uses global_load_lds (r10-verified pattern): stride-64 LDS, linear dest,
// inverse-swizzled per-lane global source column, swz() fragment reads.
__global__ __launch_bounds__(256) void gemm_bt(
    const unsigned short* __restrict__ A0, const unsigned short* __restrict__ A1,
    const unsigned short* __restrict__ B,
    const float* __restrict__ bias0, const float* __restrict__ bias1,
    const float* __restrict__ bias2, const float* __restrict__ bias3,
    const float* __restrict__ bias4,
    void* __restrict__ C,
    int M0, int M1, int K, int lda, int ldb, int ldc,
    long long sB, long long sC, long long sC2,
    float a0, int modes, int nzA)
{
  __shared__ unsigned short Al[128 * 64];
  __shared__ unsigned short Bl[128 * 64];
  const int t = threadIdx.x;
  const int w = t >> 6, l = t & 63;
  const int g = l >> 4, li = l & 15;
  const int wr = w >> 1, wc = w & 1;
  const int lr = l >> 3;                   // lane's row-in-group (== row&7 in staging)
  const int sc8 = ((t & 7) ^ lr) * 8;      // inverse-swizzled source col (shorts)
  const int row0 = blockIdx.x * 128, col0 = blockIdx.y * 128;
  const int z = blockIdx.z;
  const int Mz = (z < nzA) ? M0 : M1;
  if (row0 >= Mz) return;   // uniform early-exit for short (PK/PQ) slices
  const unsigned short* Ab = (z < nzA) ? A0 : A1;
  const unsigned short* Bb = B + (long long)z * sB;

  f32x4 acc[4][4];
#pragma unroll
  for (int m = 0; m < 4; m++)
#pragma unroll
    for (int n = 0; n < 4; n++) acc[m][n] = (f32x4){0.f, 0.f, 0.f, 0.f};

  for (int k0 = 0; k0 < K; k0 += 64) {
    __syncthreads();
#pragma unroll
    for (int i = 0; i < 4; i++) {
      const int wr0 = w * 8 + 32 * i;                    // wave-uniform LDS row base 0..120
      const int r = wr0 + lr;                            // lane's row
      gl16(&Ab[(long long)(row0 + r) * lda + k0 + sc8], &Al[wr0 * 64]);
      gl16(&Bb[(long long)(col0 + r) * ldb + k0 + sc8], &Bl[wr0 * 64]);
    }
    __syncthreads();
#pragma unroll
    for (int kk = 0; kk < 2; kk++) {
      bf16x8 af[4], bfr[4];
#pragma unroll
      for (int m = 0; m < 4; m++) af[m]  = *(bf16x8*)&Al[swz(wr * 64 + m * 16 + li, kk * 32 + g * 8)];
#pragma unroll
      for (int n = 0; n < 4; n++) bfr[n] = *(bf16x8*)&Bl[swz(wc * 64 + n * 16 + li, kk * 32 + g * 8)];
#pragma unroll
      for (int m = 0; m < 4; m++)
#pragma unroll
        for (int n = 0; n < 4; n++)
          acc[m][n] = __builtin_amdgcn_mfma_f32_16x16x32_bf16(af[m], bfr[n], acc[m][n], 0, 0, 0);
    }
  }

  const float alpha = (z == 0 || z == 4) ? a0 : 1.0f;
  const float* bias = z == 0 ? bias0 : (z == 1 ? bias1 : (z == 2 ? bias2 : (z == 3 ? bias3 : bias4)));
  const int mode = (modes >> (4 * z)) & 15;
  const long long zoff = (z < nzA) ? (long long)z * sC
                                   : (long long)nzA * sC + (long long)(z - nzA) * sC2;

#pragma unroll
  for (int m = 0; m < 4; m++) {
    int row = row0 + wr * 64 + m * 16 + g * 4;
#pragma unroll
    for (int n = 0; n < 4; n++) {
      int col = col0 + wc * 64 + n * 16 + li;
      float bv = bias ? bias[col] : 0.0f;
      if (mode == 2) {
        ushort4 st;
        st.x = f2b((acc[m][n][0] + bv) * alpha);
        st.y = f2b((acc[m][n][1] + bv) * alpha);
        st.z = f2b((acc[m][n][2] + bv) * alpha);
        st.w = f2b((acc[m][n][3] + bv) * alpha);
        *(ushort4*)&((unsigned short*)C)[zoff + (long long)col * Mz + row] = st;
      } else {
#pragma unroll
        for (int r = 0; r < 4; r++) {
          float v = (acc[m][n][r] + bv) * alpha;
          long long idx = zoff + (long long)(row + r) * ldc + col;
          if (mode == 1) ((unsigned short*)C)[idx] = f2b(v);
          else           ((float*)C)[idx] = v;
        }
      }
    }
  }
}

// ---------------- fully fused disentangled attention ----------------
// ROUND-13 STRUCTURE with ONE scheduling change: V^T staging (gl16) issues
// AFTER barrier [B] instead of in the serial [A]-[B] staging window. V^T is
// only read at PV (after [D]); prev-tile readers finished at [A]; the [C]
// barrier's vmcnt drain makes it visible long before first use. This removes
// 2 of the ~8-10 loads from the serial staging stall and hides their latency
// under the QK^T/c2p/p2c MFMA section.
// grid 1024 (flat, XCD-swizzled); block 256 (4 waves x 16 q-rows each).
// score'[q,k] = Qs.K + Qs.PK[s] + K.PQs[s], s = clamp(k-q+512, 0, 1023)
// (scale*log2e pre-folded into Q and PQ projections; softmax uses exp2)
// LDS 49152 B -> 3 blocks/CU:
//   Kl  [64][64]   K tile (shared); P tile after [D]
//   Vtl [64][64]   V^T tile, staged linearly from pre-transposed VT
//   Ct  [128][64]  persistent circular CtT[s&127][q] (raw PK in slide slots)
//   Pq  [128][64]  raw PQ window -> PtT[j][k] per tile
__global__ __launch_bounds__(256, 3) void attn_fused(
    const unsigned short* __restrict__ Qb, const unsigned short* __restrict__ Kb,
    const unsigned short* __restrict__ VT,
    const unsigned short* __restrict__ PKb, const unsigned short* __restrict__ PQb,
    unsigned short* __restrict__ ctxb)
{
  __shared__ unsigned short Kl[64 * 64];   // K tile; P tile after [D]
  __shared__ unsigned short Vtl[64 * 64];  // V^T tile
  __shared__ unsigned short Ct[128 * 64];  // circular CtT[s&127][q]
  __shared__ unsigned short Pq[128 * 64];  // raw PQ window -> PtT[j][k]

  const int t = threadIdx.x, w = t >> 6, l = t & 63, g = l >> 4, li = l & 15;
  const int lr = l >> 3;                   // lane's row-in-group (== row&7 in staging)
  const int sc8 = ((t & 7) ^ lr) * 8;      // inverse-swizzled source col (shorts)
  // XCD-aware role swizzle: each XCD gets 128 contiguous roles
  const int bid = blockIdx.x;
  const int role = (bid & 7) * 128 + (bid >> 3);
  const int q0 = (role & 15) * 64;
  const int h = (role >> 4) & 15;
  const int b = role >> 8;
  const long long qkbase = ((long long)b * TT) * DM + h * DKH;
  const long long vtb = (long long)(h * DKH) * MT + (long long)b * TT;  // + d*MT + k
  const int hbase = h * DKH;

  // Q fragments: direct global, once per block (loop-invariant)
  bf16x8 aq[2];
#pragma unroll
  for (int kk = 0; kk < 2; kk++)
    aq[kk] = *(const bf16x8*)&Qb[qkbase + (long long)(q0 + w * 16 + li) * DM + kk * 32 + g * 8];

  // ---- prologue: fill circular Ct for the kt=0 window ----
  int w0 = SPAN - q0 - 64;
  w0 = w0 < 0 ? 0 : (w0 > S2 - 128 ? S2 - 128 : w0);   // always a multiple of 64
#pragma unroll
  for (int i = 0; i < 4; i++) {
    const int wr0l = w * 8 + 32 * i;                   // logical row base 0..120
    const int jr = wr0l + lr;                          // this lane's logical row
    const int wr0 = (w0 + wr0l) & 127;                 // wrapped wave-uniform LDS row base
    gl16(&PKb[(long long)(w0 + jr) * DM + hbase + sc8], &Ct[wr0 * 64]);
  }
  __syncthreads();
  {
    f32x4 cp[8];
#pragma unroll
    for (int jb = 0; jb < 8; jb++) cp[jb] = (f32x4){0.f, 0.f, 0.f, 0.f};
    __builtin_amdgcn_s_setprio(1);
#pragma unroll
    for (int kk = 0; kk < 2; kk++)
#pragma unroll
      for (int jb = 0; jb < 8; jb++) {
        bf16x8 pkf = *(bf16x8*)&Ct[swz(jb * 16 + li, kk * 32 + g * 8)];
        cp[jb] = __builtin_amdgcn_mfma_f32_16x16x32_bf16(aq[kk], pkf, cp[jb], 0, 0, 0);
      }
    __builtin_amdgcn_s_setprio(0);
    __syncthreads();  // all raw reads done before overwrite
#pragma unroll
    for (int jb = 0; jb < 8; jb++) {
      ushort4 a;
      a.x = f2b(cp[jb][0]); a.y = f2b(cp[jb][1]);
      a.z = f2b(cp[jb][2]); a.w = f2b(cp[jb][3]);
      *(ushort4*)&Ct[swz(jb * 16 + li, w * 16 + g * 4)] = a;   // own-wave cols only
    }
  }

  f32x4 o[4];
#pragma unroll
  for (int n = 0; n < 4; n++) o[n] = (f32x4){0.f, 0.f, 0.f, 0.f};
  float mrow[4], lrow[4];
#pragma unroll
  for (int r = 0; r < 4; r++) { mrow[r] = -1e30f; lrow[r] = 0.f; }

  for (int kt = 0; kt < TT / 64; kt++) {
    const int k0 = kt * 64;
    const int d0 = k0 - q0 + SPAN;                       // block-uniform
    int w0n = d0 - 64;
    w0n = w0n < 0 ? 0 : (w0n > S2 - 128 ? S2 - 128 : w0n);
    const bool slide = (w0n != w0);                      // step is always exactly +64
    const int sb = w0 & 127;                             // slots replaced on slide (0 or 64)
    const int newrow0 = w0 + 128;                        // abs first new row on slide
    w0 = w0n;

    __syncthreads();  // [A] prev tile readers of Kl/Vtl/Ct/Pq done
    // stage K tile (global_load_lds, inverse-swizzled source); V^T deferred past [B]
#pragma unroll
    for (int i = 0; i < 2; i++) {
      const int wr0 = w * 8 + 32 * i;                    // wave-uniform LDS row base
      const int r = wr0 + lr;                            // lane's row
      gl16(&Kb[qkbase + (long long)(k0 + r) * DM + sc8], &Kl[wr0 * 64]);
    }
    // stage raw PQ window (every tile; overwritten by PtT)
#pragma unroll
    for (int i = 0; i < 4; i++) {
      const int wr0 = w * 8 + 32 * i;                    // 0..120
      const int jr = wr0 + lr;
      gl16(&PQb[(long long)(w0 + jr) * DM + hbase + sc8], &Pq[wr0 * 64]);
    }
    // stage 64 new raw PK rows on slide (into recycled Ct slots)
    if (slide) {
#pragma unroll
      for (int i = 0; i < 2; i++) {
        const int wr0l = w * 8 + 32 * i;                 // 0..56
        const int jr = wr0l + lr;
        gl16(&PKb[(long long)(newrow0 + jr) * DM + hbase + sc8], &Ct[(sb + wr0l) * 64]);
      }
    }
    __syncthreads();  // [B] K/PQ/PK staging visible (vmcnt drained by barrier)

    // V^T staging issues HERE: read only after [D]; visible by [C]'s vmcnt drain.
    // Latency hides under the MFMA section instead of the serial staging stall.
#pragma unroll
    for (int i = 0; i < 2; i++) {
      const int wr0 = w * 8 + 32 * i;
      const int r = wr0 + lr;
      gl16(&VT[vtb + (long long)r * MT + k0 + sc8], &Vtl[wr0 * 64]);
    }

    // K strip A-fragments (for p2c)
    bf16x8 ak[2];
#pragma unroll
    for (int kk = 0; kk < 2; kk++) ak[kk] = *(bf16x8*)&Kl[swz(w * 16 + li, kk * 32 + g * 8)];

    __builtin_amdgcn_s_setprio(1);
    // QK^T: 16 q-rows x 64 k-cols (Q pre-scaled by scale*log2e)
    f32x4 sc[4];
#pragma unroll
    for (int f = 0; f < 4; f++) sc[f] = (f32x4){0.f, 0.f, 0.f, 0.f};
#pragma unroll
    for (int kk = 0; kk < 2; kk++)
#pragma unroll
      for (int f = 0; f < 4; f++) {
        bf16x8 bk = *(bf16x8*)&Kl[swz(f * 16 + li, kk * 32 + g * 8)];
        sc[f] = __builtin_amdgcn_mfma_f32_16x16x32_bf16(aq[kk], bk, sc[f], 0, 0, 0);
      }
    // c2p for the 64 new slots only (slide tiles)
    f32x4 cp2[4];
#pragma unroll
    for (int jb = 0; jb < 4; jb++) cp2[jb] = (f32x4){0.f, 0.f, 0.f, 0.f};
    if (slide) {
#pragma unroll
      for (int kk = 0; kk < 2; kk++)
#pragma unroll
        for (int jb = 0; jb < 4; jb++) {
          bf16x8 pkf = *(bf16x8*)&Ct[swz(sb + jb * 16 + li, kk * 32 + g * 8)];
          cp2[jb] = __builtin_amdgcn_mfma_f32_16x16x32_bf16(aq[kk], pkf, cp2[jb], 0, 0, 0);
        }
    }
    // p2c restricted to this wave's needed rows: s in [d0+16w-63, d0+16w+15]
    int loA = d0 + w * 16 - 63; loA = loA < w0 ? w0 : loA;
    int hiA = d0 + w * 16 + 15; hiA = hiA > w0 + 127 ? w0 + 127 : hiA;
    const int jb_lo = (loA - w0) >> 4;
    const int jb_n  = ((hiA - w0) >> 4) - jb_lo;   // 0..5 inclusive extra blocks
    f32x4 pp[6];
#pragma unroll
    for (int u = 0; u < 6; u++) pp[u] = (f32x4){0.f, 0.f, 0.f, 0.f};
#pragma unroll
    for (int kk = 0; kk < 2; kk++)
#pragma unroll
      for (int u = 0; u < 6; u++)
        if (u <= jb_n) {
          bf16x8 pqf = *(bf16x8*)&Pq[swz((jb_lo + u) * 16 + li, kk * 32 + g * 8)];
          pp[u] = __builtin_amdgcn_mfma_f32_16x16x32_bf16(ak[kk], pqf, pp[u], 0, 0, 0);
        }
    __builtin_amdgcn_s_setprio(0);
    __syncthreads();  // [C] all raw window reads + Kl fragment reads done; V^T drained

    // overwrite with transposed products (own-wave columns)
    if (slide) {
#pragma unroll
      for (int jb = 0; jb < 4; jb++) {
        ushort4 a;
        a.x = f2b(cp2[jb][0]); a.y = f2b(cp2[jb][1]);
        a.z = f2b(cp2[jb][2]); a.w = f2b(cp2[jb][3]);
        *(ushort4*)&Ct[swz(sb + jb * 16 + li, w * 16 + g * 4)] = a;
      }
    }
#pragma unroll
    for (int u = 0; u < 6; u++)
      if (u <= jb_n) {
        ushort4 a;
        a.x = f2b(pp[u][0]); a.y = f2b(pp[u][1]);
        a.z = f2b(pp[u][2]); a.w = f2b(pp[u][3]);
        *(ushort4*)&Pq[swz((jb_lo + u) * 16 + li, w * 16 + g * 4)] = a;
      }
    __syncthreads();  // [D] PtT visible cross-wave (Ct gather is wave-private)

    // combine + online softmax (base-2 domain)
    float p[4][4];
    float tmax[4] = {-1e30f, -1e30f, -1e30f, -1e30f};
#pragma unroll
    for (int f = 0; f < 4; f++)
#pragma unroll
      for (int r = 0; r < 4; r++) {
        int qi = w * 16 + g * 4 + r;
        int ki = f * 16 + li;
        int sraw = d0 + ki - qi;
        int scl = sraw < 0 ? 0 : (sraw > S2 - 1 ? S2 - 1 : sraw);
        int slot = scl & 127;
        int j = scl - w0;
        float v = sc[f][r] + b2f(Ct[swz(slot, qi)]) + b2f(Pq[swz(j, ki)]);
        p[f][r] = v;
        tmax[r] = fmaxf(tmax[r], v);
      }
#pragma unroll
    for (int msk = 1; msk <= 8; msk <<= 1)
#pragma unroll
      for (int r = 0; r < 4; r++) tmax[r] = fmaxf(tmax[r], __shfl_xor(tmax[r], msk));
    float corr[4];
#pragma unroll
    for (int r = 0; r < 4; r++) {
      float mn = fmaxf(mrow[r], tmax[r]);
      corr[r] = exp2f(mrow[r] - mn);
      mrow[r] = mn;
      lrow[r] *= corr[r];
    }
#pragma unroll
    for (int n = 0; n < 4; n++)
#pragma unroll
      for (int r = 0; r < 4; r++) o[n][r] *= corr[r];

    float ps[4] = {0.f, 0.f, 0.f, 0.f};
#pragma unroll
    for (int f = 0; f < 4; f++)
#pragma unroll
      for (int r = 0; r < 4; r++) {
        float e = exp2f(p[f][r] - mrow[r]);
        ps[r] += e;
        Kl[swz(w * 16 + g * 4 + r, f * 16 + li)] = f2b(e);  // P over Kl: own wave's rows
      }
#pragma unroll
    for (int msk = 1; msk <= 8; msk <<= 1)
#pragma unroll
      for (int r = 0; r < 4; r++) ps[r] += __shfl_xor(ps[r], msk);
#pragma unroll
    for (int r = 0; r < 4; r++) lrow[r] += ps[r];

    // PV: P rows wave-private (in-wave LDS ordering by compiler); V^T from LDS
    __builtin_amdgcn_s_setprio(1);
#pragma unroll
    for (int kk = 0; kk < 2; kk++) {
      bf16x8 ap = *(bf16x8*)&Kl[swz(w * 16 + li, kk * 32 + g * 8)];
#pragma unroll
      for (int n = 0; n < 4; n++) {
        bf16x8 bvf = *(bf16x8*)&Vtl[swz(n * 16 + li, kk * 32 + g * 8)];
        o[n] = __builtin_amdgcn_mfma_f32_16x16x32_bf16(ap, bvf, o[n], 0, 0, 0);
      }
    }
    __builtin_amdgcn_s_setprio(0);
  }

  // epilogue: ctx[b, q, h*64+d] bf16
#pragma unroll
  for (int n = 0; n < 4; n++)
#pragma unroll
    for (int r = 0; r < 4; r++) {
      int q = q0 + w * 16 + g * 4 + r;
      float val = o[n][r] / lrow[r];
      ctxb[((long long)b * TT + q) * DM + h * DKH + n * 16 + li] = f2b(val);
    }
}

// ---------------- host ----------------
extern "C" void kernel_launch(void* const* d_in, const int* in_sizes, int n_in,
                              void* d_out, int out_size, void* d_ws, size_t ws_size,
                              hipStream_t stream) {
  const float* x   = (const float*)d_in[0];
  const float* Wq  = (const float*)d_in[1];
  const float* bq  = (const float*)d_in[2];
  const float* Wk  = (const float*)d_in[3];
  const float* bk  = (const float*)d_in[4];
  const float* Wv  = (const float*)d_in[5];
  const float* bv  = (const float*)d_in[6];
  const float* Wo  = (const float*)d_in[7];
  const float* bo  = (const float*)d_in[8];
  const float* Wpk = (const float*)d_in[9];
  const float* bpk = (const float*)d_in[10];
  const float* Wpq = (const float*)d_in[11];
  const float* bpq = (const float*)d_in[12];
  const float* rel = (const float*)d_in[13];

  uint8_t* ws = (uint8_t*)d_ws;
  size_t off = 0;
  auto alloc = [&](size_t bytes) -> void* {
    void* p = ws + off;
    off += (bytes + 255) & ~(size_t)255;
    return p;
  };
  // Weight order Wq,Wk,Wv,Wpk,Wpq MUST be contiguous (z-strided B in the fused launch);
  // Qb,Kb,VT,PKb,PQb MUST be contiguous (z-strided C). All sizes are 256-multiples.
  unsigned short* xb   = (unsigned short*)alloc((size_t)MT * DM * 2);
  unsigned short* Wqb  = (unsigned short*)alloc((size_t)DM * DM * 2);
  unsigned short* Wkb  = (unsigned short*)alloc((size_t)DM * DM * 2);
  unsigned short* Wvb  = (unsigned short*)alloc((size_t)DM * DM * 2);
  unsigned short* Wpkb = (unsigned short*)alloc((size_t)DM * DM * 2);
  unsigned short* Wpqb = (unsigned short*)alloc((size_t)DM * DM * 2);
  unsigned short* Wob  = (unsigned short*)alloc((size_t)DM * DM * 2);
  unsigned short* reb  = (unsigned short*)alloc((size_t)S2 * DM * 2);
  unsigned short* Qb   = (unsigned short*)alloc((size_t)MT * DM * 2);
  unsigned short* Kb   = (unsigned short*)alloc((size_t)MT * DM * 2);
  unsigned short* VT   = (unsigned short*)alloc((size_t)MT * DM * 2);  // V^T: [h*64+d][b*1024+k]
  unsigned short* PKb  = (unsigned short*)alloc((size_t)S2 * DM * 2);
  unsigned short* PQb  = (unsigned short*)alloc((size_t)S2 * DM * 2);
  unsigned short* ctxb = (unsigned short*)alloc((size_t)MT * DM * 2);

  // scale * log2(e): softmax runs in base-2 domain (exp2f)
  const float scale2 = 0.07216878364870323f * 1.4426950408889634f;

  // one batched convert launch for all 8 fp32 tensors
  CvtArgs ca;
  ca.src[0] = x;   ca.dst[0] = xb;   ca.n[0] = MT * DM;
  ca.src[1] = Wq;  ca.dst[1] = Wqb;  ca.n[1] = DM * DM;
  ca.src[2] = Wk;  ca.dst[2] = Wkb;  ca.n[2] = DM * DM;
  ca.src[3] = Wv;  ca.dst[3] = Wvb;  ca.n[3] = DM * DM;
  ca.src[4] = Wpk; ca.dst[4] = Wpkb; ca.n[4] = DM * DM;
  ca.src[5] = Wpq; ca.dst[5] = Wpqb; ca.n[5] = DM * DM;
  ca.src[6] = Wo;  ca.dst[6] = Wob;  ca.n[6] = DM * DM;
  ca.src[7] = rel; ca.dst[7] = reb;  ca.n[7] = S2 * DM;
  cvt_multi<<<dim3(1024, 8), dim3(256), 0, stream>>>(ca);

  // ALL FIVE projections in one launch:
  //   z0=Q (A=xb, alpha=scale2, bf16), z1=K (bf16), z2=V (bf16 transposed -> VT),
  //   z3=PK (A=reb, alpha=1, bf16), z4=PQ (A=reb, alpha=scale2, bf16)
  gemm_bt<<<dim3(MT / 128, DM / 128, 5), dim3(256), 0, stream>>>(
      xb, reb, Wqb,
      bq, bk, bv, bpk, bpq,
      Qb,
      MT, S2, DM, DM, DM, DM,
      (long long)DM * DM, (long long)MT * DM, (long long)S2 * DM,
      scale2, 0x11211, 3);

  // fully fused attention (flat grid, XCD-swizzled roles)
  attn_fused<<<dim3(1024), dim3(256), 0, stream>>>(
      Qb, Kb, VT, PKb, PQb, ctxb);

  // output projection: z0 only, fp32 out + bias, alpha=1
  gemm_bt<<<dim3(MT / 128, DM / 128, 1), dim3(256), 0, stream>>>(
      ctxb, ctxb, Wob,
      bo, bo, bo, bo, bo,
      d_out,
      MT, MT, DM, DM, DM, DM,
      0, 0, 0,
      1.0f, 0x0, 3);
}